// Round 8
// baseline (8987.685 us; speedup 1.0000x reference)
//
#include <hip/hip_runtime.h>
#include <cstddef>

#define BB 32
#define TT 64
#define NN_ 2048
#define SS 2048
#define DD 256
#define GG 1024
#define FLD 264 // padded feat leading dim (16B-aligned rows, >=258)

typedef __attribute__((ext_vector_type(8))) short short8;
typedef __attribute__((ext_vector_type(4))) float f32x4;

static __device__ inline unsigned short f2bf(float f) {
    union { float f; unsigned int u; } v; v.f = f;
    unsigned int u = v.u;
    unsigned int r = u + 0x7FFF + ((u >> 16) & 1);   // RNE
    return (unsigned short)(r >> 16);
}

static __device__ inline short8 pack8(float4 a, float4 b) {
    short8 s;
    s[0] = (short)f2bf(a.x); s[1] = (short)f2bf(a.y);
    s[2] = (short)f2bf(a.z); s[3] = (short)f2bf(a.w);
    s[4] = (short)f2bf(b.x); s[5] = (short)f2bf(b.y);
    s[6] = (short)f2bf(b.z); s[7] = (short)f2bf(b.w);
    return s;
}

// true iff neither 16-bit half of v equals 0x7F80 (bf16 +inf sentinel)
static __device__ inline bool ok32(unsigned int v) {
    unsigned int x = v ^ 0x7F807F80u;
    return (((x - 0x00010001u) & ~x & 0x80008000u) == 0u);
}

// ---------------- prep kernels ----------------

__global__ __launch_bounds__(256) void k_gather(const float* __restrict__ emb,
                                                const int* __restrict__ gt,
                                                const float* __restrict__ go,
                                                float* __restrict__ x) {
    int idx = blockIdx.x * 256 + threadIdx.x;     // over B*T*D = 524288
    int d = idx & (DD - 1);
    int t = (idx >> 8) & (TT - 1);
    int b = idx >> 14;
    float v;
    if (t == 0) v = go[d];
    else        v = emb[((size_t)b * NN_ + gt[b * TT + t - 1]) * DD + d];
    x[idx] = v;
}

__global__ __launch_bounds__(256) void k_first_init(int* __restrict__ firstpos) {
    int idx = blockIdx.x * 256 + threadIdx.x;     // B*N
    firstpos[idx] = TT;                            // "never picked"
}

__global__ __launch_bounds__(256) void k_first_min(const int* __restrict__ gt,
                                                   int* __restrict__ firstpos) {
    int idx = blockIdx.x * 256 + threadIdx.x;     // B*T = 2048
    int b = idx / TT;
    int t = idx % TT;
    atomicMin(&firstpos[(size_t)b * NN_ + gt[idx]], t);
}

__global__ __launch_bounds__(256) void k_poison(unsigned int* __restrict__ hbufs) {
    hbufs[(size_t)blockIdx.x * 256 + threadIdx.x] = 0x7F807F80u;  // bf16 +inf pair
}

// ctl: [0..7]=cnt per XCD, [8..15]=gdone (wave-completions), [16]=winner, [17]=done
__global__ __launch_bounds__(64) void k_zero_ctl(int* __restrict__ ctl) {
    int i = threadIdx.x;
    if (i < 32) ctl[i] = (i == 16) ? -1 : 0;
}

// hs[(b*T+t)*256 + j] <- winner hbuf[t][j>>1][b]  (bf16 -> f32)
__global__ __launch_bounds__(256) void k_h2f(const unsigned int* __restrict__ hbufs,
                                             const int* __restrict__ ctl,
                                             float* __restrict__ hs) {
    int wgrp = ctl[16];
    const unsigned int* hbuf32 = hbufs + (size_t)wgrp * TT * 4096;
    int idx = blockIdx.x * 256 + threadIdx.x;     // over B*T*D
    int j = idx & 255;
    int t = (idx >> 8) & 63;
    int b = idx >> 14;
    unsigned int w = hbuf32[(size_t)t * 4096 + (j >> 1) * 32 + b];
    unsigned short h = (j & 1) ? (unsigned short)(w >> 16) : (unsigned short)(w & 0xFFFF);
    union { unsigned int u; float f; } v;
    v.u = ((unsigned int)h) << 16;
    hs[idx] = v.f;
}

// cat = [hs | attn] : [B*T, 512]
__global__ __launch_bounds__(256) void k_cat(const float* __restrict__ hs,
                                             const float* __restrict__ attn,
                                             float* __restrict__ cat) {
    int idx = blockIdx.x * 256 + threadIdx.x;     // over B*T*512
    int d = idx & 511;
    int bt = idx >> 9;
    cat[idx] = (d < DD) ? hs[(size_t)bt * DD + d]
                        : attn[(size_t)bt * DD + (d - DD)];
}

// ---------------- bf16 MFMA NT GEMM ----------------
__global__ __launch_bounds__(256) void gemm_bf16_nt(
        const float* __restrict__ A, const float* __restrict__ Bm,
        float* __restrict__ C, int K, int lda, int ldb, int ldc,
        long sA, long sB, long sC, int Nlim,
        const float* __restrict__ bias1, const float* __restrict__ bias2,
        const int* __restrict__ firstpos, const float* __restrict__ emb_mask,
        int fscol) {
    int bz = blockIdx.z;
    A += (size_t)bz * sA; Bm += (size_t)bz * sB; C += (size_t)bz * sC;
    int tm = blockIdx.y * 64, tn = blockIdx.x * 64;
    __shared__ short Ab[64][72];
    __shared__ short Bb[64][72];
    __shared__ float sfs[64];
    int tid = threadIdx.x, lane = tid & 63, wid = tid >> 6;
    int wm = wid & 1, wn = wid >> 1;   // wave -> 32x32 quadrant

    if (fscol >= 0 && tid < 64) sfs[tid] = A[(size_t)(tm + tid) * lda + fscol];

    f32x4 zero = {0.f, 0.f, 0.f, 0.f};
    f32x4 acc[2][2] = {{zero, zero}, {zero, zero}};

    int row = tid >> 2, kk = (tid & 3) * 16;
    int brow = tn + row; if (brow >= Nlim) brow = Nlim - 1;
    const float* ap = &A[(size_t)(tm + row) * lda + kk];
    const float* bp = &Bm[(size_t)brow * ldb + kk];

    for (int k0 = 0; k0 < K; k0 += 64) {
        float4 a0 = *(const float4*)(ap + k0);
        float4 a1 = *(const float4*)(ap + k0 + 4);
        float4 a2 = *(const float4*)(ap + k0 + 8);
        float4 a3 = *(const float4*)(ap + k0 + 12);
        float4 b0 = *(const float4*)(bp + k0);
        float4 b1 = *(const float4*)(bp + k0 + 4);
        float4 b2 = *(const float4*)(bp + k0 + 8);
        float4 b3 = *(const float4*)(bp + k0 + 12);
        *(short8*)&Ab[row][kk]     = pack8(a0, a1);
        *(short8*)&Ab[row][kk + 8] = pack8(a2, a3);
        *(short8*)&Bb[row][kk]     = pack8(b0, b1);
        *(short8*)&Bb[row][kk + 8] = pack8(b2, b3);
        __syncthreads();
#pragma unroll
        for (int kt = 0; kt < 2; ++kt) {
            int k8 = kt * 32 + (lane >> 4) * 8;
            short8 fa0 = *(const short8*)&Ab[wm * 32 + (lane & 15)][k8];
            short8 fa1 = *(const short8*)&Ab[wm * 32 + 16 + (lane & 15)][k8];
            short8 fb0 = *(const short8*)&Bb[wn * 32 + (lane & 15)][k8];
            short8 fb1 = *(const short8*)&Bb[wn * 32 + 16 + (lane & 15)][k8];
            acc[0][0] = __builtin_amdgcn_mfma_f32_16x16x32_bf16(fa0, fb0, acc[0][0], 0, 0, 0);
            acc[0][1] = __builtin_amdgcn_mfma_f32_16x16x32_bf16(fa0, fb1, acc[0][1], 0, 0, 0);
            acc[1][0] = __builtin_amdgcn_mfma_f32_16x16x32_bf16(fa1, fb0, acc[1][0], 0, 0, 0);
            acc[1][1] = __builtin_amdgcn_mfma_f32_16x16x32_bf16(fa1, fb1, acc[1][1], 0, 0, 0);
        }
        __syncthreads();
    }

#pragma unroll
    for (int i = 0; i < 2; ++i) {
#pragma unroll
        for (int j = 0; j < 2; ++j) {
#pragma unroll
            for (int r = 0; r < 4; ++r) {
                int lrow = wm * 32 + i * 16 + (lane >> 4) * 4 + r;
                int gcol = tn + wn * 32 + j * 16 + (lane & 15);
                if (gcol < Nlim) {
                    float v = acc[i][j][r];
                    if (bias1) v += bias1[gcol];
                    if (bias2) v += bias2[gcol];
                    if (firstpos) {
                        int grow = tm + lrow;
                        if (firstpos[(size_t)bz * NN_ + gcol] < grow) v += sfs[lrow];
                        v -= (1.0f - emb_mask[(size_t)bz * NN_ + gcol]) * 1e20f;
                    }
                    C[(size_t)(tm + lrow) * ldc + gcol] = v;
                }
            }
        }
    }
}

// ---------------- attn = w @ enc (NN) via MFMA, B transposed at frag-read ----
__global__ __launch_bounds__(256) void gemm_attn(const float* __restrict__ W,
                                                 const float* __restrict__ enc,
                                                 float* __restrict__ attn) {
    int b = blockIdx.z;
    int tn = blockIdx.x * 64;   // d-tile
    const float* Wb = W + (size_t)b * TT * SS;
    const float* Eb = enc + (size_t)b * SS * DD;
    float* Cb = attn + (size_t)b * TT * DD;
    __shared__ short As[64][72];
    __shared__ float Bs[64][66];
    int tid = threadIdx.x, lane = tid & 63, wid = tid >> 6;
    int wm = wid & 1, wn = wid >> 1;
    f32x4 zero = {0.f, 0.f, 0.f, 0.f};
    f32x4 acc[2][2] = {{zero, zero}, {zero, zero}};
    int row = tid >> 2, kk = (tid & 3) * 16;
    const float* ap = Wb + (size_t)row * SS + kk;        // A row = t, k = s
    const float* bp = Eb + (size_t)row * DD + tn + kk;   // B row = s, col = d

    for (int k0 = 0; k0 < SS; k0 += 64) {
        float4 a0 = *(const float4*)(ap + k0);
        float4 a1 = *(const float4*)(ap + k0 + 4);
        float4 a2 = *(const float4*)(ap + k0 + 8);
        float4 a3 = *(const float4*)(ap + k0 + 12);
        *(short8*)&As[row][kk]     = pack8(a0, a1);
        *(short8*)&As[row][kk + 8] = pack8(a2, a3);
        const float* bq = bp + (size_t)k0 * DD;
#pragma unroll
        for (int i = 0; i < 8; ++i)
            *(float2*)&Bs[row][kk + 2 * i] = *(const float2*)(bq + 2 * i);
        __syncthreads();
#pragma unroll
        for (int kt = 0; kt < 2; ++kt) {
            int k8 = kt * 32 + (lane >> 4) * 8;
            short8 fa0 = *(const short8*)&As[wm * 32 + (lane & 15)][k8];
            short8 fa1 = *(const short8*)&As[wm * 32 + 16 + (lane & 15)][k8];
            short8 fb0, fb1;
#pragma unroll
            for (int e = 0; e < 8; ++e) {
                fb0[e] = (short)f2bf(Bs[k8 + e][wn * 32 + (lane & 15)]);
                fb1[e] = (short)f2bf(Bs[k8 + e][wn * 32 + 16 + (lane & 15)]);
            }
            acc[0][0] = __builtin_amdgcn_mfma_f32_16x16x32_bf16(fa0, fb0, acc[0][0], 0, 0, 0);
            acc[0][1] = __builtin_amdgcn_mfma_f32_16x16x32_bf16(fa0, fb1, acc[0][1], 0, 0, 0);
            acc[1][0] = __builtin_amdgcn_mfma_f32_16x16x32_bf16(fa1, fb0, acc[1][0], 0, 0, 0);
            acc[1][1] = __builtin_amdgcn_mfma_f32_16x16x32_bf16(fa1, fb1, acc[1][1], 0, 0, 0);
        }
        __syncthreads();
    }

#pragma unroll
    for (int i = 0; i < 2; ++i)
#pragma unroll
        for (int j = 0; j < 2; ++j)
#pragma unroll
            for (int r = 0; r < 4; ++r) {
                int lrow = wm * 32 + i * 16 + (lane >> 4) * 4 + r;
                int gcol = tn + wn * 32 + j * 16 + (lane & 15);
                Cb[(size_t)lrow * DD + gcol] = acc[i][j][r];
            }
}

// ---------------- LSTM v5: XCD-local redundant groups ----------------------
// 256 blocks; each reads HW_REG_XCC_ID and claims a rank in its XCD group.
// First 32 blocks per XCD form a group that runs the FULL LSTM redundantly,
// syncing only through the XCD-local L2: plain publish stores + sc0 polls on
// sentinel-validated data (0x7F80 impossible for h in (-1,1)). Pigeonhole
// (256 blocks / 8 XCDs) guarantees >=1 complete group. Completion counted
// per-wave (gdone==128); first complete group CASes winner + sets done;
// other groups' stuck waves escape via done (guarded by winner!=group).
__global__ __launch_bounds__(256) void k_lstm_xcd(const float* __restrict__ xW,
                                                  const float* __restrict__ Whh,
                                                  unsigned int* __restrict__ hbufs,
                                                  int* __restrict__ ctl) {
    __shared__ int sgr[2];
    int tid = threadIdx.x;
    if (tid == 0) {
        unsigned int xcc;
        asm volatile("s_getreg_b32 %0, hwreg(HW_REG_XCC_ID)" : "=s"(xcc));
        int g = (int)(xcc & 7);
        sgr[0] = g;
        sgr[1] = __hip_atomic_fetch_add(&ctl[g], 1, __ATOMIC_RELAXED,
                                        __HIP_MEMORY_SCOPE_AGENT);
    }
    __syncthreads();
    const int group = sgr[0];
    const int p = sgr[1];
    if (p >= 32) return;
    unsigned int* hbuf32 = hbufs + (size_t)group * (TT * 4096);

    int lane = tid & 63;
    int wid = tid >> 6;            // 4 waves
    int mi = wid & 1;              // unit-halves (4 units each)
    int ni = wid >> 1;             // batch-halves (16 batches each)
    int jj = lane >> 4;            // 0..3 unit within mi-group
    int bl = lane & 15;            // batch within ni-group
    int j = p * 8 + mi * 4 + jj;   // hidden unit this lane activates
    int b = ni * 16 + bl;          // batch this lane activates

    // persistent weight A-frags: row rr=lane&15 -> (g = rr&3, jw = rr>>2)
    short8 afrag[8];
    {
        int rr = lane & 15;
        const float* wrow = Whh + (size_t)((rr & 3) * 256 + p * 8 + mi * 4 + (rr >> 2)) * DD;
#pragma unroll
        for (int kt = 0; kt < 8; ++kt) {
            short8 f;
#pragma unroll
            for (int e = 0; e < 8; ++e)
                f[e] = (short)f2bf(wrow[kt * 32 + (lane >> 4) * 8 + e]);
            afrag[kt] = f;
        }
    }

    float cstate = 0.0f;
    const int wb = jj * 128 + b;   // word base: (jj*4 + w4)*32 + b
    bool dead = false;

    for (int t = 0; t < TT; ++t) {
        // xW gate biases for (b, j) -- issue before the poll
        const float* g0 = xW + ((size_t)b * TT + t) * GG + j;
        float xb0 = g0[0], xb1 = g0[256], xb2 = g0[512], xb3 = g0[768];

        f32x4 acc = {0.f, 0.f, 0.f, 0.f};
        if (t > 0) {
            const unsigned int* hb = hbuf32 + (size_t)(t - 1) * 4096;
            unsigned int q[32];
            int spin = 0;
            bool ready = false;
            while (!ready) {
#pragma unroll
                for (int i = 0; i < 32; ++i) {
                    asm volatile("global_load_dword %0, %1, off sc0"
                                 : "=v"(q[i])
                                 : "v"(&hb[(i >> 2) * 512 + wb + (i & 3) * 32])
                                 : "memory");
                }
                asm volatile("s_waitcnt vmcnt(0)" ::: "memory");
                __builtin_amdgcn_sched_barrier(0);
                ready = true;
#pragma unroll
                for (int i = 0; i < 32; ++i) ready = ready && ok32(q[i]);
                if (!ready) {
                    ++spin;
                    if ((spin & 255) == 0) {
                        if (__hip_atomic_load(&ctl[17], __ATOMIC_ACQUIRE,
                                              __HIP_MEMORY_SCOPE_AGENT) != 0 &&
                            __hip_atomic_load(&ctl[16], __ATOMIC_RELAXED,
                                              __HIP_MEMORY_SCOPE_AGENT) != group) {
                            dead = true;
                            break;
                        }
                    }
                }
            }
            if (dead) break;
#pragma unroll
            for (int kt = 0; kt < 8; ++kt) {
                union { unsigned int w[4]; short8 s; } u;
                u.w[0] = q[kt * 4 + 0]; u.w[1] = q[kt * 4 + 1];
                u.w[2] = q[kt * 4 + 2]; u.w[3] = q[kt * 4 + 3];
                acc = __builtin_amdgcn_mfma_f32_16x16x32_bf16(afrag[kt], u.s, acc, 0, 0, 0);
            }
        }

        float pi = xb0 + acc[0];
        float pf = xb1 + acc[1];
        float pg = xb2 + acc[2];
        float po = xb3 + acc[3];
        float ig = 1.0f / (1.0f + __expf(-pi));
        float fg = 1.0f / (1.0f + __expf(-pf));
        float gg = tanhf(pg);
        float og = 1.0f / (1.0f + __expf(-po));
        cstate = fg * cstate + ig * gg;
        float hn = og * tanhf(cstate);

        // publish (j, j+1) pair for batch b: plain store -> local L2
        float hnb = __shfl_down(hn, 16);
        if ((jj & 1) == 0) {
            unsigned int wv = (unsigned int)f2bf(hn) |
                              ((unsigned int)f2bf(hnb) << 16);
            hbuf32[(size_t)t * 4096 + (p * 4 + mi * 2 + (jj >> 1)) * 32 + b] = wv;
        }
        // drain so publishes don't queue behind next step's polls
        asm volatile("s_waitcnt vmcnt(0)" ::: "memory");
    }

    // per-wave completion accounting (wave completion proves all producers
    // it consumed published through t=62 and its own t=63 publish drained)
    if ((tid & 63) == 0 && !dead) {
        int r = __hip_atomic_fetch_add(&ctl[8 + group], 1, __ATOMIC_ACQ_REL,
                                       __HIP_MEMORY_SCOPE_AGENT);
        if (r == 127) {
            int expect = -1;
            __hip_atomic_compare_exchange_strong(&ctl[16], &expect, group,
                __ATOMIC_ACQ_REL, __ATOMIC_RELAXED, __HIP_MEMORY_SCOPE_AGENT);
            __hip_atomic_store(&ctl[17], 1, __ATOMIC_RELEASE,
                               __HIP_MEMORY_SCOPE_AGENT);
        }
    }
}

// ---------------- softmax over S (in place, masked) ----------------
__global__ __launch_bounds__(256) void k_softmax(float* __restrict__ raw,
                                                 const float* __restrict__ enc_mask) {
    int bt = blockIdx.x;
    int b = bt / TT;
    float* r = raw + (size_t)bt * SS;
    __shared__ float row[SS];
    __shared__ float red[16];
    int tid = threadIdx.x;
    float mx = -1e30f;
    for (int s = tid; s < SS; s += 256) {
        float v = r[s] - (1.0f - enc_mask[(size_t)b * SS + s]) * 1e20f;
        row[s] = v;
        mx = fmaxf(mx, v);
    }
#pragma unroll
    for (int o = 32; o > 0; o >>= 1) mx = fmaxf(mx, __shfl_down(mx, o));
    if ((tid & 63) == 0) red[tid >> 6] = mx;
    __syncthreads();
    if (tid == 0) {
        float m2 = red[0];
        for (int i = 1; i < 4; ++i) m2 = fmaxf(m2, red[i]);
        red[0] = m2;
    }
    __syncthreads();
    mx = red[0];
    float sum = 0.0f;
    for (int s = tid; s < SS; s += 256) {
        float e = expf(row[s] - mx);
        row[s] = e;
        sum += e;
    }
#pragma unroll
    for (int o = 32; o > 0; o >>= 1) sum += __shfl_down(sum, o);
    if ((tid & 63) == 0) red[8 + (tid >> 6)] = sum;
    __syncthreads();
    if (tid == 0) {
        float s = red[8];
        for (int i = 1; i < 4; ++i) s += red[8 + i];
        red[8] = s;
    }
    __syncthreads();
    float inv = 1.0f / red[8];
    for (int s = tid; s < SS; s += 256) r[s] = row[s] * inv;
}

// ---------------- launch ----------------
extern "C" void kernel_launch(void* const* d_in, const int* in_sizes, int n_in,
                              void* d_out, int out_size, void* d_ws, size_t ws_size,
                              hipStream_t stream) {
    const float* emb      = (const float*)d_in[0];
    const float* emb_mask = (const float*)d_in[1];
    const float* enc      = (const float*)d_in[2];
    const float* enc_mask = (const float*)d_in[3];
    const int*   gt       = (const int*)d_in[4];
    const float* go       = (const float*)d_in[5];
    const float* Wih      = (const float*)d_in[6];
    const float* Whh      = (const float*)d_in[7];
    const float* bih      = (const float*)d_in[8];
    const float* bhh      = (const float*)d_in[9];
    const float* Wdt      = (const float*)d_in[10];
    const float* bdt      = (const float*)d_in[11];
    const float* Wf       = (const float*)d_in[12];
    const float* bf       = (const float*)d_in[13];
    float* out = (float*)d_out;

    float* ws    = (float*)d_ws;
    float* x     = ws;                                   // [B*T*D]
    float* xW    = x     + (size_t)BB * TT * DD;         // [B*T*G]
    float* hs    = xW    + (size_t)BB * TT * GG;         // [B*T*D]
    float* dec   = hs    + (size_t)BB * TT * DD;         // [B*T*D]
    float* w     = dec   + (size_t)BB * TT * DD;         // [B*T*S]
    float* attn  = w     + (size_t)BB * TT * SS;         // [B*T*D]
    float* feat  = attn  + (size_t)BB * TT * DD;         // [B*T*FLD]
    float* cat   = feat  + (size_t)BB * TT * FLD;        // [B*T*512]
    float* cat_end = cat + (size_t)BB * TT * 512;
    int* firstpos = (int*)cat_end;                       // [B*N]
    int* ctl      = firstpos + (size_t)BB * NN_;         // [64]
    unsigned int* hbufs = (unsigned int*)(ctl + 64);     // 8 x [T*4096] u32 (8MB)

    k_gather<<<BB * TT * DD / 256, 256, 0, stream>>>(emb, gt, go, x);
    k_first_init<<<BB * NN_ / 256, 256, 0, stream>>>(firstpos);
    k_first_min<<<BB * TT / 256, 256, 0, stream>>>(gt, firstpos);
    k_zero_ctl<<<1, 64, 0, stream>>>(ctl);
    k_poison<<<8 * TT * 4096 / 256, 256, 0, stream>>>(hbufs);

    // xW = x @ Wih^T + bih + bhh : [2048,1024]
    gemm_bf16_nt<<<dim3(GG / 64, BB * TT / 64, 1), 256, 0, stream>>>(
        x, Wih, xW, DD, DD, DD, GG, 0, 0, 0, GG,
        bih, bhh, nullptr, nullptr, -1);

    k_lstm_xcd<<<256, 256, 0, stream>>>(xW, Whh, hbufs, ctl);

    // hs (f32) from winner hbuf (bf16)
    k_h2f<<<BB * TT * DD / 256, 256, 0, stream>>>(hbufs, ctl, hs);

    // dec = hs @ Wdt^T + bdt : [2048,256]
    gemm_bf16_nt<<<dim3(DD / 64, BB * TT / 64, 1), 256, 0, stream>>>(
        hs, Wdt, dec, DD, DD, DD, DD, 0, 0, 0, DD,
        bdt, nullptr, nullptr, nullptr, -1);

    // raw[b] = dec[b] @ enc[b]^T : [64,2048], batch 32
    gemm_bf16_nt<<<dim3(SS / 64, 1, BB), 256, 0, stream>>>(
        dec, enc, w, DD, DD, DD, SS,
        (long)TT * DD, (long)SS * DD, (long)TT * SS, SS,
        nullptr, nullptr, nullptr, nullptr, -1);

    k_softmax<<<BB * TT, 256, 0, stream>>>(w, enc_mask);

    // attn[b] = w[b] @ enc[b] : [64,256], batch 32  (MFMA, inline transpose)
    gemm_attn<<<dim3(DD / 64, 1, BB), 256, 0, stream>>>(w, enc, attn);

    // cat = [hs | attn]
    k_cat<<<BB * TT * 512 / 256, 256, 0, stream>>>(hs, attn, cat);

    // feat = cat @ Wf^T + bf : [2048, 257] (ld FLD)
    gemm_bf16_nt<<<dim3(5, BB * TT / 64, 1), 256, 0, stream>>>(
        cat, Wf, feat, 2 * DD, 2 * DD, 2 * DD, FLD, 0, 0, 0, DD + 1,
        bf, nullptr, nullptr, nullptr, -1);

    // score[b] = feat[b,:, :256] @ emb[b]^T (+ picked, mask)
    gemm_bf16_nt<<<dim3(NN_ / 64, 1, BB), 256, 0, stream>>>(
        feat, emb, out, DD, FLD, DD, NN_,
        (long)TT * FLD, (long)NN_ * DD, (long)TT * NN_, NN_,
        nullptr, nullptr, firstpos, emb_mask, 256);
}

// Round 9
// 451.127 us; speedup vs baseline: 19.9227x; 19.9227x over previous
//
#include <hip/hip_runtime.h>
#include <cstddef>

#define BB 32
#define TT 64
#define NN_ 2048
#define SS 2048
#define DD 256
#define GG 1024
#define FLD 264 // padded feat leading dim (16B-aligned rows, >=258)

typedef __attribute__((ext_vector_type(8))) short short8;
typedef __attribute__((ext_vector_type(4))) float f32x4;

static __device__ inline unsigned short f2bf(float f) {
    union { float f; unsigned int u; } v; v.f = f;
    unsigned int u = v.u;
    unsigned int r = u + 0x7FFF + ((u >> 16) & 1);   // RNE
    return (unsigned short)(r >> 16);
}

static __device__ inline short8 pack8(float4 a, float4 b) {
    short8 s;
    s[0] = (short)f2bf(a.x); s[1] = (short)f2bf(a.y);
    s[2] = (short)f2bf(a.z); s[3] = (short)f2bf(a.w);
    s[4] = (short)f2bf(b.x); s[5] = (short)f2bf(b.y);
    s[6] = (short)f2bf(b.z); s[7] = (short)f2bf(b.w);
    return s;
}

// true iff neither 16-bit half of v equals 0x7F80 (bf16 +inf sentinel)
static __device__ inline bool ok32(unsigned int v) {
    unsigned int x = v ^ 0x7F807F80u;
    return (((x - 0x00010001u) & ~x & 0x80008000u) == 0u);
}

// ---------------- prep kernels ----------------

__global__ __launch_bounds__(256) void k_gather(const float* __restrict__ emb,
                                                const int* __restrict__ gt,
                                                const float* __restrict__ go,
                                                float* __restrict__ x) {
    int idx = blockIdx.x * 256 + threadIdx.x;     // over B*T*D = 524288
    int d = idx & (DD - 1);
    int t = (idx >> 8) & (TT - 1);
    int b = idx >> 14;
    float v;
    if (t == 0) v = go[d];
    else        v = emb[((size_t)b * NN_ + gt[b * TT + t - 1]) * DD + d];
    x[idx] = v;
}

__global__ __launch_bounds__(256) void k_first_init(int* __restrict__ firstpos) {
    int idx = blockIdx.x * 256 + threadIdx.x;     // B*N
    firstpos[idx] = TT;                            // "never picked"
}

__global__ __launch_bounds__(256) void k_first_min(const int* __restrict__ gt,
                                                   int* __restrict__ firstpos) {
    int idx = blockIdx.x * 256 + threadIdx.x;     // B*T = 2048
    int b = idx / TT;
    int t = idx % TT;
    atomicMin(&firstpos[(size_t)b * NN_ + gt[idx]], t);
}

__global__ __launch_bounds__(256) void k_poison(unsigned int* __restrict__ hbuf32) {
    hbuf32[(size_t)blockIdx.x * 256 + threadIdx.x] = 0x7F807F80u;  // bf16 +inf pair
}

// hs[(b*T+t)*256 + j] <- hbuf32[t][j>>1][b]  (bf16 -> f32)
__global__ __launch_bounds__(256) void k_h2f(const unsigned int* __restrict__ hbuf32,
                                             float* __restrict__ hs) {
    int idx = blockIdx.x * 256 + threadIdx.x;     // over B*T*D
    int j = idx & 255;
    int t = (idx >> 8) & 63;
    int b = idx >> 14;
    unsigned int w = hbuf32[(size_t)t * 4096 + (j >> 1) * 32 + b];
    unsigned short h = (j & 1) ? (unsigned short)(w >> 16) : (unsigned short)(w & 0xFFFF);
    union { unsigned int u; float f; } v;
    v.u = ((unsigned int)h) << 16;
    hs[idx] = v.f;
}

// cat = [hs | attn] : [B*T, 512]
__global__ __launch_bounds__(256) void k_cat(const float* __restrict__ hs,
                                             const float* __restrict__ attn,
                                             float* __restrict__ cat) {
    int idx = blockIdx.x * 256 + threadIdx.x;     // over B*T*512
    int d = idx & 511;
    int bt = idx >> 9;
    cat[idx] = (d < DD) ? hs[(size_t)bt * DD + d]
                        : attn[(size_t)bt * DD + (d - DD)];
}

// ---------------- bf16 MFMA NT GEMM ----------------
__global__ __launch_bounds__(256) void gemm_bf16_nt(
        const float* __restrict__ A, const float* __restrict__ Bm,
        float* __restrict__ C, int K, int lda, int ldb, int ldc,
        long sA, long sB, long sC, int Nlim,
        const float* __restrict__ bias1, const float* __restrict__ bias2,
        const int* __restrict__ firstpos, const float* __restrict__ emb_mask,
        int fscol) {
    int bz = blockIdx.z;
    A += (size_t)bz * sA; Bm += (size_t)bz * sB; C += (size_t)bz * sC;
    int tm = blockIdx.y * 64, tn = blockIdx.x * 64;
    __shared__ short Ab[64][72];
    __shared__ short Bb[64][72];
    __shared__ float sfs[64];
    int tid = threadIdx.x, lane = tid & 63, wid = tid >> 6;
    int wm = wid & 1, wn = wid >> 1;   // wave -> 32x32 quadrant

    if (fscol >= 0 && tid < 64) sfs[tid] = A[(size_t)(tm + tid) * lda + fscol];

    f32x4 zero = {0.f, 0.f, 0.f, 0.f};
    f32x4 acc[2][2] = {{zero, zero}, {zero, zero}};

    int row = tid >> 2, kk = (tid & 3) * 16;
    int brow = tn + row; if (brow >= Nlim) brow = Nlim - 1;
    const float* ap = &A[(size_t)(tm + row) * lda + kk];
    const float* bp = &Bm[(size_t)brow * ldb + kk];

    for (int k0 = 0; k0 < K; k0 += 64) {
        float4 a0 = *(const float4*)(ap + k0);
        float4 a1 = *(const float4*)(ap + k0 + 4);
        float4 a2 = *(const float4*)(ap + k0 + 8);
        float4 a3 = *(const float4*)(ap + k0 + 12);
        float4 b0 = *(const float4*)(bp + k0);
        float4 b1 = *(const float4*)(bp + k0 + 4);
        float4 b2 = *(const float4*)(bp + k0 + 8);
        float4 b3 = *(const float4*)(bp + k0 + 12);
        *(short8*)&Ab[row][kk]     = pack8(a0, a1);
        *(short8*)&Ab[row][kk + 8] = pack8(a2, a3);
        *(short8*)&Bb[row][kk]     = pack8(b0, b1);
        *(short8*)&Bb[row][kk + 8] = pack8(b2, b3);
        __syncthreads();
#pragma unroll
        for (int kt = 0; kt < 2; ++kt) {
            int k8 = kt * 32 + (lane >> 4) * 8;
            short8 fa0 = *(const short8*)&Ab[wm * 32 + (lane & 15)][k8];
            short8 fa1 = *(const short8*)&Ab[wm * 32 + 16 + (lane & 15)][k8];
            short8 fb0 = *(const short8*)&Bb[wn * 32 + (lane & 15)][k8];
            short8 fb1 = *(const short8*)&Bb[wn * 32 + 16 + (lane & 15)][k8];
            acc[0][0] = __builtin_amdgcn_mfma_f32_16x16x32_bf16(fa0, fb0, acc[0][0], 0, 0, 0);
            acc[0][1] = __builtin_amdgcn_mfma_f32_16x16x32_bf16(fa0, fb1, acc[0][1], 0, 0, 0);
            acc[1][0] = __builtin_amdgcn_mfma_f32_16x16x32_bf16(fa1, fb0, acc[1][0], 0, 0, 0);
            acc[1][1] = __builtin_amdgcn_mfma_f32_16x16x32_bf16(fa1, fb1, acc[1][1], 0, 0, 0);
        }
        __syncthreads();
    }

#pragma unroll
    for (int i = 0; i < 2; ++i) {
#pragma unroll
        for (int j = 0; j < 2; ++j) {
#pragma unroll
            for (int r = 0; r < 4; ++r) {
                int lrow = wm * 32 + i * 16 + (lane >> 4) * 4 + r;
                int gcol = tn + wn * 32 + j * 16 + (lane & 15);
                if (gcol < Nlim) {
                    float v = acc[i][j][r];
                    if (bias1) v += bias1[gcol];
                    if (bias2) v += bias2[gcol];
                    if (firstpos) {
                        int grow = tm + lrow;
                        if (firstpos[(size_t)bz * NN_ + gcol] < grow) v += sfs[lrow];
                        v -= (1.0f - emb_mask[(size_t)bz * NN_ + gcol]) * 1e20f;
                    }
                    C[(size_t)(tm + lrow) * ldc + gcol] = v;
                }
            }
        }
    }
}

// ---------------- attn = w @ enc (NN) via MFMA, B transposed at frag-read ----
__global__ __launch_bounds__(256) void gemm_attn(const float* __restrict__ W,
                                                 const float* __restrict__ enc,
                                                 float* __restrict__ attn) {
    int b = blockIdx.z;
    int tn = blockIdx.x * 64;   // d-tile
    const float* Wb = W + (size_t)b * TT * SS;
    const float* Eb = enc + (size_t)b * SS * DD;
    float* Cb = attn + (size_t)b * TT * DD;
    __shared__ short As[64][72];
    __shared__ float Bs[64][66];
    int tid = threadIdx.x, lane = tid & 63, wid = tid >> 6;
    int wm = wid & 1, wn = wid >> 1;
    f32x4 zero = {0.f, 0.f, 0.f, 0.f};
    f32x4 acc[2][2] = {{zero, zero}, {zero, zero}};
    int row = tid >> 2, kk = (tid & 3) * 16;
    const float* ap = Wb + (size_t)row * SS + kk;        // A row = t, k = s
    const float* bp = Eb + (size_t)row * DD + tn + kk;   // B row = s, col = d

    for (int k0 = 0; k0 < SS; k0 += 64) {
        float4 a0 = *(const float4*)(ap + k0);
        float4 a1 = *(const float4*)(ap + k0 + 4);
        float4 a2 = *(const float4*)(ap + k0 + 8);
        float4 a3 = *(const float4*)(ap + k0 + 12);
        *(short8*)&As[row][kk]     = pack8(a0, a1);
        *(short8*)&As[row][kk + 8] = pack8(a2, a3);
        const float* bq = bp + (size_t)k0 * DD;
#pragma unroll
        for (int i = 0; i < 8; ++i)
            *(float2*)&Bs[row][kk + 2 * i] = *(const float2*)(bq + 2 * i);
        __syncthreads();
#pragma unroll
        for (int kt = 0; kt < 2; ++kt) {
            int k8 = kt * 32 + (lane >> 4) * 8;
            short8 fa0 = *(const short8*)&As[wm * 32 + (lane & 15)][k8];
            short8 fa1 = *(const short8*)&As[wm * 32 + 16 + (lane & 15)][k8];
            short8 fb0, fb1;
#pragma unroll
            for (int e = 0; e < 8; ++e) {
                fb0[e] = (short)f2bf(Bs[k8 + e][wn * 32 + (lane & 15)]);
                fb1[e] = (short)f2bf(Bs[k8 + e][wn * 32 + 16 + (lane & 15)]);
            }
            acc[0][0] = __builtin_amdgcn_mfma_f32_16x16x32_bf16(fa0, fb0, acc[0][0], 0, 0, 0);
            acc[0][1] = __builtin_amdgcn_mfma_f32_16x16x32_bf16(fa0, fb1, acc[0][1], 0, 0, 0);
            acc[1][0] = __builtin_amdgcn_mfma_f32_16x16x32_bf16(fa1, fb0, acc[1][0], 0, 0, 0);
            acc[1][1] = __builtin_amdgcn_mfma_f32_16x16x32_bf16(fa1, fb1, acc[1][1], 0, 0, 0);
        }
        __syncthreads();
    }

#pragma unroll
    for (int i = 0; i < 2; ++i)
#pragma unroll
        for (int j = 0; j < 2; ++j)
#pragma unroll
            for (int r = 0; r < 4; ++r) {
                int lrow = wm * 32 + i * 16 + (lane >> 4) * 4 + r;
                int gcol = tn + wn * 32 + j * 16 + (lane & 15);
                Cb[(size_t)lrow * DD + gcol] = acc[i][j][r];
            }
}

// ---------------- LSTM v6: 8 blocks x 512 threads, data-poll protocol ------
// Round-6 protocol (flagless sentinel data-poll via agent atomics) with 4x
// fewer producer blocks: tail latency waits on 8 producers instead of 32 and
// poll traffic drops 4x. Block p owns 32 hidden units; wave (ni,ui) runs two
// passes (mi) of the transposed-MFMA shape: A = Whh-slice (rows = 4 units x
// 4 gates), B = h fragments from polled words. In-lane activation, 2
// c-states per lane, publish paired-bf16 u32, prompt vmcnt drain.
__global__ __launch_bounds__(512) void k_lstm_mfma8(const float* __restrict__ xW,
                                                    const float* __restrict__ Whh,
                                                    unsigned int* __restrict__ hbuf32) {
    int p = blockIdx.x;            // 0..7: units p*32 .. p*32+31
    int tid = threadIdx.x;
    int lane = tid & 63;
    int wid = tid >> 6;            // 8 waves
    int ni = wid & 1;              // batch half (16 batches)
    int ui = wid >> 1;             // unit quad within block (8 units)
    int jj = lane >> 4;            // 0..3
    int bl = lane & 15;
    int b = ni * 16 + bl;          // batch this lane activates

    // persistent weight A-frags for both passes
    short8 afrag[2][8];
#pragma unroll
    for (int mi = 0; mi < 2; ++mi) {
        int rr = lane & 15;
        int unit = p * 32 + ui * 8 + mi * 4 + (rr >> 2);
        const float* wrow = Whh + (size_t)((rr & 3) * 256 + unit) * DD;
#pragma unroll
        for (int kt = 0; kt < 8; ++kt) {
            short8 f;
#pragma unroll
            for (int e = 0; e < 8; ++e)
                f[e] = (short)f2bf(wrow[kt * 32 + jj * 8 + e]);
            afrag[mi][kt] = f;
        }
    }

    float cst0 = 0.0f, cst1 = 0.0f;
    const int wb = jj * 128 + b;   // poll word base
    const int u0 = p * 32 + ui * 8 + jj;       // pass-0 unit
    const int u1 = u0 + 4;                     // pass-1 unit
    const int base2 = (p * 32 + ui * 8) >> 1;  // word row base for publish

    for (int t = 0; t < TT; ++t) {
        // xW gate biases for both passes -- issue before the poll
        const float* g0 = xW + ((size_t)b * TT + t) * GG;
        float x00 = g0[u0], x01 = g0[256 + u0], x02 = g0[512 + u0], x03 = g0[768 + u0];
        float x10 = g0[u1], x11 = g0[256 + u1], x12 = g0[512 + u1], x13 = g0[768 + u1];

        unsigned int q[32];
        if (t > 0) {
            const unsigned int* hb = hbuf32 + (size_t)(t - 1) * 4096;
            bool ready = false;
            while (!ready) {
                ready = true;
#pragma unroll
                for (int kt = 0; kt < 8; ++kt)
#pragma unroll
                    for (int w4 = 0; w4 < 4; ++w4)
                        q[kt * 4 + w4] = __hip_atomic_load(&hb[kt * 512 + wb + w4 * 32],
                            __ATOMIC_RELAXED, __HIP_MEMORY_SCOPE_AGENT);
#pragma unroll
                for (int i = 0; i < 32; ++i) ready = ready && ok32(q[i]);
            }
        }

#pragma unroll
        for (int mi = 0; mi < 2; ++mi) {
            f32x4 acc = {0.f, 0.f, 0.f, 0.f};
            if (t > 0) {
#pragma unroll
                for (int kt = 0; kt < 8; ++kt) {
                    union { unsigned int w[4]; short8 s; } u;
                    u.w[0] = q[kt * 4 + 0]; u.w[1] = q[kt * 4 + 1];
                    u.w[2] = q[kt * 4 + 2]; u.w[3] = q[kt * 4 + 3];
                    acc = __builtin_amdgcn_mfma_f32_16x16x32_bf16(afrag[mi][kt], u.s, acc, 0, 0, 0);
                }
            }
            float pi = (mi ? x10 : x00) + acc[0];
            float pf = (mi ? x11 : x01) + acc[1];
            float pg = (mi ? x12 : x02) + acc[2];
            float po = (mi ? x13 : x03) + acc[3];
            float ig = 1.0f / (1.0f + __expf(-pi));
            float fg = 1.0f / (1.0f + __expf(-pf));
            float gg = tanhf(pg);
            float og = 1.0f / (1.0f + __expf(-po));
            float c = (mi ? cst1 : cst0);
            c = fg * c + ig * gg;
            float hn = og * tanhf(c);
            if (mi) cst1 = c; else cst0 = c;

            // publish pair (u, u+1): lanes jj and jj+1 are 16 apart
            float hnb = __shfl_down(hn, 16);
            if (!(jj & 1)) {
                unsigned int wv = (unsigned int)f2bf(hn) |
                                  ((unsigned int)f2bf(hnb) << 16);
                __hip_atomic_store(&hbuf32[(size_t)t * 4096 +
                                           (base2 + mi * 2 + (jj >> 1)) * 32 + b],
                                   wv, __ATOMIC_RELAXED, __HIP_MEMORY_SCOPE_AGENT);
            }
        }
        // drain so publishes don't queue behind next step's polls
        asm volatile("s_waitcnt vmcnt(0)" ::: "memory");
    }
}

// ---------------- softmax over S (in place, masked) ----------------
__global__ __launch_bounds__(256) void k_softmax(float* __restrict__ raw,
                                                 const float* __restrict__ enc_mask) {
    int bt = blockIdx.x;
    int b = bt / TT;
    float* r = raw + (size_t)bt * SS;
    __shared__ float row[SS];
    __shared__ float red[16];
    int tid = threadIdx.x;
    float mx = -1e30f;
    for (int s = tid; s < SS; s += 256) {
        float v = r[s] - (1.0f - enc_mask[(size_t)b * SS + s]) * 1e20f;
        row[s] = v;
        mx = fmaxf(mx, v);
    }
#pragma unroll
    for (int o = 32; o > 0; o >>= 1) mx = fmaxf(mx, __shfl_down(mx, o));
    if ((tid & 63) == 0) red[tid >> 6] = mx;
    __syncthreads();
    if (tid == 0) {
        float m2 = red[0];
        for (int i = 1; i < 4; ++i) m2 = fmaxf(m2, red[i]);
        red[0] = m2;
    }
    __syncthreads();
    mx = red[0];
    float sum = 0.0f;
    for (int s = tid; s < SS; s += 256) {
        float e = expf(row[s] - mx);
        row[s] = e;
        sum += e;
    }
#pragma unroll
    for (int o = 32; o > 0; o >>= 1) sum += __shfl_down(sum, o);
    if ((tid & 63) == 0) red[8 + (tid >> 6)] = sum;
    __syncthreads();
    if (tid == 0) {
        float s = red[8];
        for (int i = 1; i < 4; ++i) s += red[8 + i];
        red[8] = s;
    }
    __syncthreads();
    float inv = 1.0f / red[8];
    for (int s = tid; s < SS; s += 256) r[s] = row[s] * inv;
}

// ---------------- launch ----------------
extern "C" void kernel_launch(void* const* d_in, const int* in_sizes, int n_in,
                              void* d_out, int out_size, void* d_ws, size_t ws_size,
                              hipStream_t stream) {
    const float* emb      = (const float*)d_in[0];
    const float* emb_mask = (const float*)d_in[1];
    const float* enc      = (const float*)d_in[2];
    const float* enc_mask = (const float*)d_in[3];
    const int*   gt       = (const int*)d_in[4];
    const float* go       = (const float*)d_in[5];
    const float* Wih      = (const float*)d_in[6];
    const float* Whh      = (const float*)d_in[7];
    const float* bih      = (const float*)d_in[8];
    const float* bhh      = (const float*)d_in[9];
    const float* Wdt      = (const float*)d_in[10];
    const float* bdt      = (const float*)d_in[11];
    const float* Wf       = (const float*)d_in[12];
    const float* bf       = (const float*)d_in[13];
    float* out = (float*)d_out;

    float* ws    = (float*)d_ws;
    float* x     = ws;                                   // [B*T*D]
    float* xW    = x     + (size_t)BB * TT * DD;         // [B*T*G]
    float* hs    = xW    + (size_t)BB * TT * GG;         // [B*T*D]
    float* dec   = hs    + (size_t)BB * TT * DD;         // [B*T*D]
    float* w     = dec   + (size_t)BB * TT * DD;         // [B*T*S]
    float* attn  = w     + (size_t)BB * TT * SS;         // [B*T*D]
    float* feat  = attn  + (size_t)BB * TT * DD;         // [B*T*FLD]
    float* cat   = feat  + (size_t)BB * TT * FLD;        // [B*T*512]
    float* cat_end = cat + (size_t)BB * TT * 512;
    int* firstpos = (int*)cat_end;                       // [B*N]
    unsigned int* hbuf32 = (unsigned int*)(firstpos + (size_t)BB * NN_); // [T*4096] u32 (1MB)

    k_gather<<<BB * TT * DD / 256, 256, 0, stream>>>(emb, gt, go, x);
    k_first_init<<<BB * NN_ / 256, 256, 0, stream>>>(firstpos);
    k_first_min<<<BB * TT / 256, 256, 0, stream>>>(gt, firstpos);
    k_poison<<<TT * 4096 / 256, 256, 0, stream>>>(hbuf32);

    // xW = x @ Wih^T + bih + bhh : [2048,1024]
    gemm_bf16_nt<<<dim3(GG / 64, BB * TT / 64, 1), 256, 0, stream>>>(
        x, Wih, xW, DD, DD, DD, GG, 0, 0, 0, GG,
        bih, bhh, nullptr, nullptr, -1);

    k_lstm_mfma8<<<8, 512, 0, stream>>>(xW, Whh, hbuf32);

    // hs (f32) from hbuf (bf16)
    k_h2f<<<BB * TT * DD / 256, 256, 0, stream>>>(hbuf32, hs);

    // dec = hs @ Wdt^T + bdt : [2048,256]
    gemm_bf16_nt<<<dim3(DD / 64, BB * TT / 64, 1), 256, 0, stream>>>(
        hs, Wdt, dec, DD, DD, DD, DD, 0, 0, 0, DD,
        bdt, nullptr, nullptr, nullptr, -1);

    // raw[b] = dec[b] @ enc[b]^T : [64,2048], batch 32
    gemm_bf16_nt<<<dim3(SS / 64, 1, BB), 256, 0, stream>>>(
        dec, enc, w, DD, DD, DD, SS,
        (long)TT * DD, (long)SS * DD, (long)TT * SS, SS,
        nullptr, nullptr, nullptr, nullptr, -1);

    k_softmax<<<BB * TT, 256, 0, stream>>>(w, enc_mask);

    // attn[b] = w[b] @ enc[b] : [64,256], batch 32  (MFMA, inline transpose)
    gemm_attn<<<dim3(DD / 64, 1, BB), 256, 0, stream>>>(w, enc, attn);

    // cat = [hs | attn]
    k_cat<<<BB * TT * 512 / 256, 256, 0, stream>>>(hs, attn, cat);

    // feat = cat @ Wf^T + bf : [2048, 257] (ld FLD)
    gemm_bf16_nt<<<dim3(5, BB * TT / 64, 1), 256, 0, stream>>>(
        cat, Wf, feat, 2 * DD, 2 * DD, 2 * DD, FLD, 0, 0, 0, DD + 1,
        bf, nullptr, nullptr, nullptr, -1);

    // score[b] = feat[b,:, :256] @ emb[b]^T (+ picked, mask)
    gemm_bf16_nt<<<dim3(NN_ / 64, 1, BB), 256, 0, stream>>>(
        feat, emb, out, DD, FLD, DD, NN_,
        (long)TT * FLD, (long)NN_ * DD, (long)TT * NN_, NN_,
        nullptr, nullptr, firstpos, emb_mask, 256);
}

// Round 10
// 288.139 us; speedup vs baseline: 31.1922x; 1.5657x over previous
//
#include <hip/hip_runtime.h>
#include <cstddef>

#define BB 32
#define TT 64
#define NN_ 2048
#define SS 2048
#define DD 256
#define GG 1024
#define LP 32   // LSTM blocks (col-slices)
#define FLD 264 // padded feat leading dim (16B-aligned rows, >=258)

typedef __attribute__((ext_vector_type(8))) short short8;
typedef __attribute__((ext_vector_type(4))) float f32x4;

static __device__ inline unsigned short f2bf(float f) {
    union { float f; unsigned int u; } v; v.f = f;
    unsigned int u = v.u;
    unsigned int r = u + 0x7FFF + ((u >> 16) & 1);   // RNE
    return (unsigned short)(r >> 16);
}

static __device__ inline short8 pack8(float4 a, float4 b) {
    short8 s;
    s[0] = (short)f2bf(a.x); s[1] = (short)f2bf(a.y);
    s[2] = (short)f2bf(a.z); s[3] = (short)f2bf(a.w);
    s[4] = (short)f2bf(b.x); s[5] = (short)f2bf(b.y);
    s[6] = (short)f2bf(b.z); s[7] = (short)f2bf(b.w);
    return s;
}

// true iff neither 16-bit half of v equals 0x7F80 (bf16 +inf sentinel)
static __device__ inline bool ok32(unsigned int v) {
    unsigned int x = v ^ 0x7F807F80u;
    return (((x - 0x00010001u) & ~x & 0x80008000u) == 0u);
}

// ---------------- prep kernels ----------------

__global__ __launch_bounds__(256) void k_first_init(int* __restrict__ firstpos) {
    int idx = blockIdx.x * 256 + threadIdx.x;     // B*N
    firstpos[idx] = TT;                            // "never picked"
}

__global__ __launch_bounds__(256) void k_first_min(const int* __restrict__ gt,
                                                   int* __restrict__ firstpos) {
    int idx = blockIdx.x * 256 + threadIdx.x;     // B*T = 2048
    int b = idx / TT;
    int t = idx % TT;
    atomicMin(&firstpos[(size_t)b * NN_ + gt[idx]], t);
}

__global__ __launch_bounds__(256) void k_poison(unsigned int* __restrict__ hbuf32) {
    hbuf32[(size_t)blockIdx.x * 256 + threadIdx.x] = 0x7F807F80u;  // bf16 +inf pair
}

// ---------------- xW GEMM with fused teacher-forcing gather ----------------
// xW[bt, n] = sum_k x[bt,k]*Wih[n,k] + bih[n] + bhh[n],
// x[bt] = go (t==0) else emb[b, gt[b,t-1]]
__global__ __launch_bounds__(256) void gemm_xw(
        const float* __restrict__ emb, const int* __restrict__ gt,
        const float* __restrict__ go, const float* __restrict__ Wih,
        float* __restrict__ xW,
        const float* __restrict__ bih, const float* __restrict__ bhh) {
    int tm = blockIdx.y * 64, tn = blockIdx.x * 64;
    __shared__ short Ab[64][72];
    __shared__ short Bb[64][72];
    int tid = threadIdx.x, lane = tid & 63, wid = tid >> 6;
    int wm = wid & 1, wn = wid >> 1;
    f32x4 zero = {0.f, 0.f, 0.f, 0.f};
    f32x4 acc[2][2] = {{zero, zero}, {zero, zero}};
    int row = tid >> 2, kk = (tid & 3) * 16;
    int m = tm + row, b = m >> 6, t = m & 63;
    const float* arow = (t == 0) ? go
        : emb + ((size_t)b * NN_ + gt[b * TT + t - 1]) * DD;
    const float* ap = arow + kk;
    const float* bp = Wih + (size_t)(tn + row) * DD + kk;

    for (int k0 = 0; k0 < DD; k0 += 64) {
        float4 a0 = *(const float4*)(ap + k0);
        float4 a1 = *(const float4*)(ap + k0 + 4);
        float4 a2 = *(const float4*)(ap + k0 + 8);
        float4 a3 = *(const float4*)(ap + k0 + 12);
        float4 b0 = *(const float4*)(bp + k0);
        float4 b1 = *(const float4*)(bp + k0 + 4);
        float4 b2 = *(const float4*)(bp + k0 + 8);
        float4 b3 = *(const float4*)(bp + k0 + 12);
        *(short8*)&Ab[row][kk]     = pack8(a0, a1);
        *(short8*)&Ab[row][kk + 8] = pack8(a2, a3);
        *(short8*)&Bb[row][kk]     = pack8(b0, b1);
        *(short8*)&Bb[row][kk + 8] = pack8(b2, b3);
        __syncthreads();
#pragma unroll
        for (int kt = 0; kt < 2; ++kt) {
            int k8 = kt * 32 + (lane >> 4) * 8;
            short8 fa0 = *(const short8*)&Ab[wm * 32 + (lane & 15)][k8];
            short8 fa1 = *(const short8*)&Ab[wm * 32 + 16 + (lane & 15)][k8];
            short8 fb0 = *(const short8*)&Bb[wn * 32 + (lane & 15)][k8];
            short8 fb1 = *(const short8*)&Bb[wn * 32 + 16 + (lane & 15)][k8];
            acc[0][0] = __builtin_amdgcn_mfma_f32_16x16x32_bf16(fa0, fb0, acc[0][0], 0, 0, 0);
            acc[0][1] = __builtin_amdgcn_mfma_f32_16x16x32_bf16(fa0, fb1, acc[0][1], 0, 0, 0);
            acc[1][0] = __builtin_amdgcn_mfma_f32_16x16x32_bf16(fa1, fb0, acc[1][0], 0, 0, 0);
            acc[1][1] = __builtin_amdgcn_mfma_f32_16x16x32_bf16(fa1, fb1, acc[1][1], 0, 0, 0);
        }
        __syncthreads();
    }

#pragma unroll
    for (int i = 0; i < 2; ++i)
#pragma unroll
        for (int j = 0; j < 2; ++j)
#pragma unroll
            for (int r = 0; r < 4; ++r) {
                int lrow = wm * 32 + i * 16 + (lane >> 4) * 4 + r;
                int gcol = tn + wn * 32 + j * 16 + (lane & 15);
                xW[(size_t)(tm + lrow) * GG + gcol] = acc[0][0][0] * 0.0f +
                    ((i == 0) ? (j == 0 ? acc[0][0][r] : acc[0][1][r])
                              : (j == 0 ? acc[1][0][r] : acc[1][1][r])) +
                    bih[gcol] + bhh[gcol];
            }
}

// ---------------- generic bf16 MFMA NT GEMM (f32 A/B) ----------------------
__global__ __launch_bounds__(256) void gemm_bf16_nt(
        const float* __restrict__ A, const float* __restrict__ Bm,
        float* __restrict__ C, int K, int lda, int ldb, int ldc,
        long sA, long sB, long sC, int Nlim,
        const float* __restrict__ bias1,
        const int* __restrict__ firstpos, const float* __restrict__ emb_mask,
        int fscol) {
    int bz = blockIdx.z;
    A += (size_t)bz * sA; Bm += (size_t)bz * sB; C += (size_t)bz * sC;
    int tm = blockIdx.y * 64, tn = blockIdx.x * 64;
    __shared__ short Ab[64][72];
    __shared__ short Bb[64][72];
    __shared__ float sfs[64];
    int tid = threadIdx.x, lane = tid & 63, wid = tid >> 6;
    int wm = wid & 1, wn = wid >> 1;

    if (fscol >= 0 && tid < 64) sfs[tid] = A[(size_t)(tm + tid) * lda + fscol];

    f32x4 zero = {0.f, 0.f, 0.f, 0.f};
    f32x4 acc[2][2] = {{zero, zero}, {zero, zero}};

    int row = tid >> 2, kk = (tid & 3) * 16;
    int brow = tn + row; if (brow >= Nlim) brow = Nlim - 1;
    const float* ap = &A[(size_t)(tm + row) * lda + kk];
    const float* bp = &Bm[(size_t)brow * ldb + kk];

    for (int k0 = 0; k0 < K; k0 += 64) {
        float4 a0 = *(const float4*)(ap + k0);
        float4 a1 = *(const float4*)(ap + k0 + 4);
        float4 a2 = *(const float4*)(ap + k0 + 8);
        float4 a3 = *(const float4*)(ap + k0 + 12);
        float4 b0 = *(const float4*)(bp + k0);
        float4 b1 = *(const float4*)(bp + k0 + 4);
        float4 b2 = *(const float4*)(bp + k0 + 8);
        float4 b3 = *(const float4*)(bp + k0 + 12);
        *(short8*)&Ab[row][kk]     = pack8(a0, a1);
        *(short8*)&Ab[row][kk + 8] = pack8(a2, a3);
        *(short8*)&Bb[row][kk]     = pack8(b0, b1);
        *(short8*)&Bb[row][kk + 8] = pack8(b2, b3);
        __syncthreads();
#pragma unroll
        for (int kt = 0; kt < 2; ++kt) {
            int k8 = kt * 32 + (lane >> 4) * 8;
            short8 fa0 = *(const short8*)&Ab[wm * 32 + (lane & 15)][k8];
            short8 fa1 = *(const short8*)&Ab[wm * 32 + 16 + (lane & 15)][k8];
            short8 fb0 = *(const short8*)&Bb[wn * 32 + (lane & 15)][k8];
            short8 fb1 = *(const short8*)&Bb[wn * 32 + 16 + (lane & 15)][k8];
            acc[0][0] = __builtin_amdgcn_mfma_f32_16x16x32_bf16(fa0, fb0, acc[0][0], 0, 0, 0);
            acc[0][1] = __builtin_amdgcn_mfma_f32_16x16x32_bf16(fa0, fb1, acc[0][1], 0, 0, 0);
            acc[1][0] = __builtin_amdgcn_mfma_f32_16x16x32_bf16(fa1, fb0, acc[1][0], 0, 0, 0);
            acc[1][1] = __builtin_amdgcn_mfma_f32_16x16x32_bf16(fa1, fb1, acc[1][1], 0, 0, 0);
        }
        __syncthreads();
    }

#pragma unroll
    for (int i = 0; i < 2; ++i) {
#pragma unroll
        for (int j = 0; j < 2; ++j) {
#pragma unroll
            for (int r = 0; r < 4; ++r) {
                int lrow = wm * 32 + i * 16 + (lane >> 4) * 4 + r;
                int gcol = tn + wn * 32 + j * 16 + (lane & 15);
                if (gcol < Nlim) {
                    float v = acc[i][j][r];
                    if (bias1) v += bias1[gcol];
                    if (firstpos) {
                        int grow = tm + lrow;
                        if (firstpos[(size_t)bz * NN_ + gcol] < grow) v += sfs[lrow];
                        v -= (1.0f - emb_mask[(size_t)bz * NN_ + gcol]) * 1e20f;
                    }
                    C[(size_t)(tm + lrow) * ldc + gcol] = v;
                }
            }
        }
    }
}

// ---------------- dec = hs16(bf16) @ Wdt^T + bdt ---------------------------
__global__ __launch_bounds__(256) void gemm_dec(
        const unsigned int* __restrict__ hs16, const float* __restrict__ Wdt,
        float* __restrict__ dec, const float* __restrict__ bdt) {
    int tm = blockIdx.y * 64, tn = blockIdx.x * 64;
    __shared__ short Ab[64][72];
    __shared__ short Bb[64][72];
    int tid = threadIdx.x, lane = tid & 63, wid = tid >> 6;
    int wm = wid & 1, wn = wid >> 1;
    f32x4 zero = {0.f, 0.f, 0.f, 0.f};
    f32x4 acc[2][2] = {{zero, zero}, {zero, zero}};
    int row = tid >> 2, kk = (tid & 3) * 16;
    const short* ap16 = (const short*)hs16 + (size_t)(tm + row) * DD + kk;
    const float* bp = Wdt + (size_t)(tn + row) * DD + kk;

    for (int k0 = 0; k0 < DD; k0 += 64) {
        *(short8*)&Ab[row][kk]     = *(const short8*)(ap16 + k0);
        *(short8*)&Ab[row][kk + 8] = *(const short8*)(ap16 + k0 + 8);
        float4 b0 = *(const float4*)(bp + k0);
        float4 b1 = *(const float4*)(bp + k0 + 4);
        float4 b2 = *(const float4*)(bp + k0 + 8);
        float4 b3 = *(const float4*)(bp + k0 + 12);
        *(short8*)&Bb[row][kk]     = pack8(b0, b1);
        *(short8*)&Bb[row][kk + 8] = pack8(b2, b3);
        __syncthreads();
#pragma unroll
        for (int kt = 0; kt < 2; ++kt) {
            int k8 = kt * 32 + (lane >> 4) * 8;
            short8 fa0 = *(const short8*)&Ab[wm * 32 + (lane & 15)][k8];
            short8 fa1 = *(const short8*)&Ab[wm * 32 + 16 + (lane & 15)][k8];
            short8 fb0 = *(const short8*)&Bb[wn * 32 + (lane & 15)][k8];
            short8 fb1 = *(const short8*)&Bb[wn * 32 + 16 + (lane & 15)][k8];
            acc[0][0] = __builtin_amdgcn_mfma_f32_16x16x32_bf16(fa0, fb0, acc[0][0], 0, 0, 0);
            acc[0][1] = __builtin_amdgcn_mfma_f32_16x16x32_bf16(fa0, fb1, acc[0][1], 0, 0, 0);
            acc[1][0] = __builtin_amdgcn_mfma_f32_16x16x32_bf16(fa1, fb0, acc[1][0], 0, 0, 0);
            acc[1][1] = __builtin_amdgcn_mfma_f32_16x16x32_bf16(fa1, fb1, acc[1][1], 0, 0, 0);
        }
        __syncthreads();
    }

#pragma unroll
    for (int i = 0; i < 2; ++i)
#pragma unroll
        for (int j = 0; j < 2; ++j)
#pragma unroll
            for (int r = 0; r < 4; ++r) {
                int lrow = wm * 32 + i * 16 + (lane >> 4) * 4 + r;
                int gcol = tn + wn * 32 + j * 16 + (lane & 15);
                dec[(size_t)(tm + lrow) * DD + gcol] = acc[i][j][r] + bdt[gcol];
            }
}

// ---------------- feat = [hs16 | attn] @ Wf^T + bf (fused cat) -------------
__global__ __launch_bounds__(256) void gemm_feat(
        const unsigned int* __restrict__ hs16, const float* __restrict__ attn,
        const float* __restrict__ Wf, const float* __restrict__ bf,
        float* __restrict__ feat) {
    int tm = blockIdx.y * 64, tn = blockIdx.x * 64;
    __shared__ short Ab[64][72];
    __shared__ short Bb[64][72];
    int tid = threadIdx.x, lane = tid & 63, wid = tid >> 6;
    int wm = wid & 1, wn = wid >> 1;
    f32x4 zero = {0.f, 0.f, 0.f, 0.f};
    f32x4 acc[2][2] = {{zero, zero}, {zero, zero}};
    int row = tid >> 2, kk = (tid & 3) * 16;
    int brow = tn + row; if (brow > 256) brow = 256;
    const short* a16 = (const short*)hs16 + (size_t)(tm + row) * DD + kk;
    const float* af  = attn + (size_t)(tm + row) * DD + kk;
    const float* bp  = Wf + (size_t)brow * (2 * DD) + kk;

    for (int k0 = 0; k0 < 2 * DD; k0 += 64) {
        if (k0 < DD) {
            *(short8*)&Ab[row][kk]     = *(const short8*)(a16 + k0);
            *(short8*)&Ab[row][kk + 8] = *(const short8*)(a16 + k0 + 8);
        } else {
            float4 a0 = *(const float4*)(af + k0 - DD);
            float4 a1 = *(const float4*)(af + k0 - DD + 4);
            float4 a2 = *(const float4*)(af + k0 - DD + 8);
            float4 a3 = *(const float4*)(af + k0 - DD + 12);
            *(short8*)&Ab[row][kk]     = pack8(a0, a1);
            *(short8*)&Ab[row][kk + 8] = pack8(a2, a3);
        }
        float4 b0 = *(const float4*)(bp + k0);
        float4 b1 = *(const float4*)(bp + k0 + 4);
        float4 b2 = *(const float4*)(bp + k0 + 8);
        float4 b3 = *(const float4*)(bp + k0 + 12);
        *(short8*)&Bb[row][kk]     = pack8(b0, b1);
        *(short8*)&Bb[row][kk + 8] = pack8(b2, b3);
        __syncthreads();
#pragma unroll
        for (int kt = 0; kt < 2; ++kt) {
            int k8 = kt * 32 + (lane >> 4) * 8;
            short8 fa0 = *(const short8*)&Ab[wm * 32 + (lane & 15)][k8];
            short8 fa1 = *(const short8*)&Ab[wm * 32 + 16 + (lane & 15)][k8];
            short8 fb0 = *(const short8*)&Bb[wn * 32 + (lane & 15)][k8];
            short8 fb1 = *(const short8*)&Bb[wn * 32 + 16 + (lane & 15)][k8];
            acc[0][0] = __builtin_amdgcn_mfma_f32_16x16x32_bf16(fa0, fb0, acc[0][0], 0, 0, 0);
            acc[0][1] = __builtin_amdgcn_mfma_f32_16x16x32_bf16(fa0, fb1, acc[0][1], 0, 0, 0);
            acc[1][0] = __builtin_amdgcn_mfma_f32_16x16x32_bf16(fa1, fb0, acc[1][0], 0, 0, 0);
            acc[1][1] = __builtin_amdgcn_mfma_f32_16x16x32_bf16(fa1, fb1, acc[1][1], 0, 0, 0);
        }
        __syncthreads();
    }

#pragma unroll
    for (int i = 0; i < 2; ++i)
#pragma unroll
        for (int j = 0; j < 2; ++j)
#pragma unroll
            for (int r = 0; r < 4; ++r) {
                int lrow = wm * 32 + i * 16 + (lane >> 4) * 4 + r;
                int gcol = tn + wn * 32 + j * 16 + (lane & 15);
                if (gcol < DD + 1)
                    feat[(size_t)(tm + lrow) * FLD + gcol] = acc[i][j][r] + bf[gcol];
            }
}

// ---------------- attn = w @ enc (NN) via MFMA, B transposed at frag-read ----
__global__ __launch_bounds__(256) void gemm_attn(const float* __restrict__ W,
                                                 const float* __restrict__ enc,
                                                 float* __restrict__ attn) {
    int b = blockIdx.z;
    int tn = blockIdx.x * 64;   // d-tile
    const float* Wb = W + (size_t)b * TT * SS;
    const float* Eb = enc + (size_t)b * SS * DD;
    float* Cb = attn + (size_t)b * TT * DD;
    __shared__ short As[64][72];
    __shared__ float Bs[64][66];
    int tid = threadIdx.x, lane = tid & 63, wid = tid >> 6;
    int wm = wid & 1, wn = wid >> 1;
    f32x4 zero = {0.f, 0.f, 0.f, 0.f};
    f32x4 acc[2][2] = {{zero, zero}, {zero, zero}};
    int row = tid >> 2, kk = (tid & 3) * 16;
    const float* ap = Wb + (size_t)row * SS + kk;        // A row = t, k = s
    const float* bp = Eb + (size_t)row * DD + tn + kk;   // B row = s, col = d

    for (int k0 = 0; k0 < SS; k0 += 64) {
        float4 a0 = *(const float4*)(ap + k0);
        float4 a1 = *(const float4*)(ap + k0 + 4);
        float4 a2 = *(const float4*)(ap + k0 + 8);
        float4 a3 = *(const float4*)(ap + k0 + 12);
        *(short8*)&As[row][kk]     = pack8(a0, a1);
        *(short8*)&As[row][kk + 8] = pack8(a2, a3);
        const float* bq = bp + (size_t)k0 * DD;
#pragma unroll
        for (int i = 0; i < 8; ++i)
            *(float2*)&Bs[row][kk + 2 * i] = *(const float2*)(bq + 2 * i);
        __syncthreads();
#pragma unroll
        for (int kt = 0; kt < 2; ++kt) {
            int k8 = kt * 32 + (lane >> 4) * 8;
            short8 fa0 = *(const short8*)&As[wm * 32 + (lane & 15)][k8];
            short8 fa1 = *(const short8*)&As[wm * 32 + 16 + (lane & 15)][k8];
            short8 fb0, fb1;
#pragma unroll
            for (int e = 0; e < 8; ++e) {
                fb0[e] = (short)f2bf(Bs[k8 + e][wn * 32 + (lane & 15)]);
                fb1[e] = (short)f2bf(Bs[k8 + e][wn * 32 + 16 + (lane & 15)]);
            }
            acc[0][0] = __builtin_amdgcn_mfma_f32_16x16x32_bf16(fa0, fb0, acc[0][0], 0, 0, 0);
            acc[0][1] = __builtin_amdgcn_mfma_f32_16x16x32_bf16(fa0, fb1, acc[0][1], 0, 0, 0);
            acc[1][0] = __builtin_amdgcn_mfma_f32_16x16x32_bf16(fa1, fb0, acc[1][0], 0, 0, 0);
            acc[1][1] = __builtin_amdgcn_mfma_f32_16x16x32_bf16(fa1, fb1, acc[1][1], 0, 0, 0);
        }
        __syncthreads();
    }

#pragma unroll
    for (int i = 0; i < 2; ++i)
#pragma unroll
        for (int j = 0; j < 2; ++j)
#pragma unroll
            for (int r = 0; r < 4; ++r) {
                int lrow = wm * 32 + i * 16 + (lane >> 4) * 4 + r;
                int gcol = tn + wn * 32 + j * 16 + (lane & 15);
                Cb[(size_t)lrow * DD + gcol] = acc[i][j][r];
            }
}

// ---------------- LSTM (round-6 proven): transposed MFMA, in-lane act ------
// 32 blocks x 256 threads; flagless data-poll protocol (sentinel 0x7F80);
// publishes hbuf32[t][j>>1][b] AND row-major bf16 hs16[bt][j>>1].
__global__ __launch_bounds__(256) void k_lstm_mfma(const float* __restrict__ xW,
                                                   const float* __restrict__ Whh,
                                                   unsigned int* __restrict__ hbuf32,
                                                   unsigned int* __restrict__ hs16) {
    int p = blockIdx.x;            // 0..31 col-slice
    int tid = threadIdx.x;
    int lane = tid & 63;
    int wid = tid >> 6;            // 4 waves
    int mi = wid & 1;              // unit-halves (4 units each)
    int ni = wid >> 1;             // batch-halves (16 batches each)
    int jj = lane >> 4;            // 0..3 unit within mi-group
    int bl = lane & 15;            // batch within ni-group
    int j = p * 8 + mi * 4 + jj;   // hidden unit this lane activates
    int b = ni * 16 + bl;          // batch this lane activates

    // persistent weight A-frags: row rr=lane&15 -> (g = rr&3, jw = rr>>2)
    short8 afrag[8];
    {
        int rr = lane & 15;
        const float* wrow = Whh + (size_t)((rr & 3) * 256 + p * 8 + mi * 4 + (rr >> 2)) * DD;
#pragma unroll
        for (int kt = 0; kt < 8; ++kt) {
            short8 f;
#pragma unroll
            for (int e = 0; e < 8; ++e)
                f[e] = (short)f2bf(wrow[kt * 32 + (lane >> 4) * 8 + e]);
            afrag[kt] = f;
        }
    }

    float cstate = 0.0f;
    const int wb = jj * 128 + b;   // word base: (jj*4 + w4)*32 + b

    for (int t = 0; t < TT; ++t) {
        // xW gate biases for (b, j) -- issue before the poll
        const float* g0 = xW + ((size_t)b * TT + t) * GG + j;
        float xb0 = g0[0], xb1 = g0[256], xb2 = g0[512], xb3 = g0[768];

        f32x4 acc = {0.f, 0.f, 0.f, 0.f};
        if (t > 0) {
            const unsigned int* hb = hbuf32 + (size_t)(t - 1) * 4096;
            unsigned int q[32];
            bool ready = false;
            while (!ready) {
                ready = true;
#pragma unroll
                for (int kt = 0; kt < 8; ++kt)
#pragma unroll
                    for (int w4 = 0; w4 < 4; ++w4)
                        q[kt * 4 + w4] = __hip_atomic_load(&hb[kt * 512 + wb + w4 * 32],
                            __ATOMIC_RELAXED, __HIP_MEMORY_SCOPE_AGENT);
#pragma unroll
                for (int i = 0; i < 32; ++i) ready = ready && ok32(q[i]);
            }
#pragma unroll
            for (int kt = 0; kt < 8; ++kt) {
                union { unsigned int w[4]; short8 s; } u;
                u.w[0] = q[kt * 4 + 0]; u.w[1] = q[kt * 4 + 1];
                u.w[2] = q[kt * 4 + 2]; u.w[3] = q[kt * 4 + 3];
                acc = __builtin_amdgcn_mfma_f32_16x16x32_bf16(afrag[kt], u.s, acc, 0, 0, 0);
            }
        }

        float pi = xb0 + acc[0];
        float pf = xb1 + acc[1];
        float pg = xb2 + acc[2];
        float po = xb3 + acc[3];
        float ig = 1.0f / (1.0f + __expf(-pi));
        float fg = 1.0f / (1.0f + __expf(-pf));
        float gg = tanhf(pg);
        float og = 1.0f / (1.0f + __expf(-po));
        cstate = fg * cstate + ig * gg;
        float hn = og * tanhf(cstate);

        // publish (j, j+1) pair for batch b
        float hnb = __shfl_down(hn, 16);
        if ((jj & 1) == 0) {
            unsigned int wv = (unsigned int)f2bf(hn) |
                              ((unsigned int)f2bf(hnb) << 16);
            int jp = p * 4 + mi * 2 + (jj >> 1);
            __hip_atomic_store(&hbuf32[(size_t)t * 4096 + jp * 32 + b],
                               wv, __ATOMIC_RELAXED, __HIP_MEMORY_SCOPE_AGENT);
            hs16[((size_t)b * TT + t) * 128 + jp] = wv;   // row-major bf16 hs
        }
        // drain promptly so stores don't queue behind next step's polls
        asm volatile("s_waitcnt vmcnt(0)" ::: "memory");
    }
}

// ---------------- softmax over S (in place, masked) ----------------
__global__ __launch_bounds__(256) void k_softmax(float* __restrict__ raw,
                                                 const float* __restrict__ enc_mask) {
    int bt = blockIdx.x;
    int b = bt / TT;
    float* r = raw + (size_t)bt * SS;
    __shared__ float row[SS];
    __shared__ float red[16];
    int tid = threadIdx.x;
    float mx = -1e30f;
    for (int s = tid; s < SS; s += 256) {
        float v = r[s] - (1.0f - enc_mask[(size_t)b * SS + s]) * 1e20f;
        row[s] = v;
        mx = fmaxf(mx, v);
    }
#pragma unroll
    for (int o = 32; o > 0; o >>= 1) mx = fmaxf(mx, __shfl_down(mx, o));
    if ((tid & 63) == 0) red[tid >> 6] = mx;
    __syncthreads();
    if (tid == 0) {
        float m2 = red[0];
        for (int i = 1; i < 4; ++i) m2 = fmaxf(m2, red[i]);
        red[0] = m2;
    }
    __syncthreads();
    mx = red[0];
    float sum = 0.0f;
    for (int s = tid; s < SS; s += 256) {
        float e = expf(row[s] - mx);
        row[s] = e;
        sum += e;
    }
#pragma unroll
    for (int o = 32; o > 0; o >>= 1) sum += __shfl_down(sum, o);
    if ((tid & 63) == 0) red[8 + (tid >> 6)] = sum;
    __syncthreads();
    if (tid == 0) {
        float s = red[8];
        for (int i = 1; i < 4; ++i) s += red[8 + i];
        red[8] = s;
    }
    __syncthreads();
    float inv = 1.0f / red[8];
    for (int s = tid; s < SS; s += 256) r[s] = row[s] * inv;
}

// ---------------- launch ----------------
extern "C" void kernel_launch(void* const* d_in, const int* in_sizes, int n_in,
                              void* d_out, int out_size, void* d_ws, size_t ws_size,
                              hipStream_t stream) {
    const float* emb      = (const float*)d_in[0];
    const float* emb_mask = (const float*)d_in[1];
    const float* enc      = (const float*)d_in[2];
    const float* enc_mask = (const float*)d_in[3];
    const int*   gt       = (const int*)d_in[4];
    const float* go       = (const float*)d_in[5];
    const float* Wih      = (const float*)d_in[6];
    const float* Whh      = (const float*)d_in[7];
    const float* bih      = (const float*)d_in[8];
    const float* bhh      = (const float*)d_in[9];
    const float* Wdt      = (const float*)d_in[10];
    const float* bdt      = (const float*)d_in[11];
    const float* Wf       = (const float*)d_in[12];
    const float* bf       = (const float*)d_in[13];
    float* out = (float*)d_out;

    float* ws    = (float*)d_ws;
    float* xW    = ws;                                   // [B*T*G]
    float* dec   = xW   + (size_t)BB * TT * GG;          // [B*T*D]
    float* w     = dec  + (size_t)BB * TT * DD;          // [B*T*S]
    float* attn  = w    + (size_t)BB * TT * SS;          // [B*T*D]
    float* feat  = attn + (size_t)BB * TT * DD;          // [B*T*FLD]
    float* feat_end = feat + (size_t)BB * TT * FLD;
    int* firstpos = (int*)feat_end;                      // [B*N]
    unsigned int* hbuf32 = (unsigned int*)(firstpos + (size_t)BB * NN_); // [T*4096] (1MB)
    unsigned int* hs16   = hbuf32 + (size_t)TT * 4096;   // [B*T*128] (1MB)

    k_first_init<<<BB * NN_ / 256, 256, 0, stream>>>(firstpos);
    k_first_min<<<BB * TT / 256, 256, 0, stream>>>(gt, firstpos);
    k_poison<<<TT * 4096 / 256, 256, 0, stream>>>(hbuf32);

    // xW = x @ Wih^T + bih + bhh (gather fused) : [2048,1024]
    gemm_xw<<<dim3(GG / 64, BB * TT / 64, 1), 256, 0, stream>>>(
        emb, gt, go, Wih, xW, bih, bhh);

    k_lstm_mfma<<<LP, 256, 0, stream>>>(xW, Whh, hbuf32, hs16);

    // dec = hs16 @ Wdt^T + bdt : [2048,256]
    gemm_dec<<<dim3(DD / 64, BB * TT / 64, 1), 256, 0, stream>>>(
        hs16, Wdt, dec, bdt);

    // raw[b] = dec[b] @ enc[b]^T : [64,2048], batch 32
    gemm_bf16_nt<<<dim3(SS / 64, 1, BB), 256, 0, stream>>>(
        dec, enc, w, DD, DD, DD, SS,
        (long)TT * DD, (long)SS * DD, (long)TT * SS, SS,
        nullptr, nullptr, nullptr, -1);

    k_softmax<<<BB * TT, 256, 0, stream>>>(w, enc_mask);

    // attn[b] = w[b] @ enc[b] : [64,256], batch 32  (MFMA, inline transpose)
    gemm_attn<<<dim3(DD / 64, 1, BB), 256, 0, stream>>>(w, enc, attn);

    // feat = [hs16|attn] @ Wf^T + bf : [2048, 257] (cat fused, ld FLD)
    gemm_feat<<<dim3(5, BB * TT / 64, 1), 256, 0, stream>>>(
        hs16, attn, Wf, bf, feat);

    // score[b] = feat[b,:, :256] @ emb[b]^T (+ picked, mask)
    gemm_bf16_nt<<<dim3(NN_ / 64, 1, BB), 256, 0, stream>>>(
        feat, emb, out, DD, FLD, DD, NN_,
        (long)TT * FLD, (long)NN_ * DD, (long)TT * NN_, NN_,
        nullptr, firstpos, emb_mask, 256);
}

// Round 11
// 249.898 us; speedup vs baseline: 35.9655x; 1.1530x over previous
//
#include <hip/hip_runtime.h>
#include <cstddef>

#define BB 32
#define TT 64
#define NN_ 2048
#define SS 2048
#define DD 256
#define GG 1024
#define LP 32   // LSTM blocks (col-slices)
#define FLD 264 // padded feat leading dim (16B-aligned rows, >=258)

typedef __attribute__((ext_vector_type(8))) short short8;
typedef __attribute__((ext_vector_type(4))) float f32x4;

static __device__ inline unsigned short f2bf(float f) {
    union { float f; unsigned int u; } v; v.f = f;
    unsigned int u = v.u;
    unsigned int r = u + 0x7FFF + ((u >> 16) & 1);   // RNE
    return (unsigned short)(r >> 16);
}

static __device__ inline short8 pack8(float4 a, float4 b) {
    short8 s;
    s[0] = (short)f2bf(a.x); s[1] = (short)f2bf(a.y);
    s[2] = (short)f2bf(a.z); s[3] = (short)f2bf(a.w);
    s[4] = (short)f2bf(b.x); s[5] = (short)f2bf(b.y);
    s[6] = (short)f2bf(b.z); s[7] = (short)f2bf(b.w);
    return s;
}

// true iff neither 16-bit half of v equals 0x7F80 (bf16 +inf sentinel)
static __device__ inline bool ok32(unsigned int v) {
    unsigned int x = v ^ 0x7F807F80u;
    return (((x - 0x00010001u) & ~x & 0x80008000u) == 0u);
}

// ---------------- prep: firstpos (scan, no atomics) + hbuf poison ----------
__global__ __launch_bounds__(256) void k_prep(const int* __restrict__ gt,
                                              int* __restrict__ firstpos,
                                              unsigned int* __restrict__ hbuf32) {
    int T = blockIdx.x * 256 + threadIdx.x;   // 0..65535 over B*N
    int b = T >> 11, n = T & 2047;
    const int* g = gt + b * TT;
    int ft = TT;
#pragma unroll
    for (int t = 0; t < TT; ++t)
        if (g[t] == n && t < ft) ft = t;
    firstpos[T] = ft;
#pragma unroll
    for (int k = 0; k < 4; ++k)
        hbuf32[T + 65536 * k] = 0x7F807F80u;   // bf16 +inf pairs
}

// ---------------- xW GEMM with fused teacher-forcing gather ----------------
__global__ __launch_bounds__(256) void gemm_xw(
        const float* __restrict__ emb, const int* __restrict__ gt,
        const float* __restrict__ go, const float* __restrict__ Wih,
        float* __restrict__ xW,
        const float* __restrict__ bih, const float* __restrict__ bhh) {
    int tm = blockIdx.y * 64, tn = blockIdx.x * 64;
    __shared__ short Ab[64][72];
    __shared__ short Bb[64][72];
    int tid = threadIdx.x, lane = tid & 63, wid = tid >> 6;
    int wm = wid & 1, wn = wid >> 1;
    f32x4 zero = {0.f, 0.f, 0.f, 0.f};
    f32x4 acc[2][2] = {{zero, zero}, {zero, zero}};
    int row = tid >> 2, kk = (tid & 3) * 16;
    int m = tm + row, b = m >> 6, t = m & 63;
    const float* arow = (t == 0) ? go
        : emb + ((size_t)b * NN_ + gt[b * TT + t - 1]) * DD;
    const float* ap = arow + kk;
    const float* bp = Wih + (size_t)(tn + row) * DD + kk;

    for (int k0 = 0; k0 < DD; k0 += 64) {
        float4 a0 = *(const float4*)(ap + k0);
        float4 a1 = *(const float4*)(ap + k0 + 4);
        float4 a2 = *(const float4*)(ap + k0 + 8);
        float4 a3 = *(const float4*)(ap + k0 + 12);
        float4 b0 = *(const float4*)(bp + k0);
        float4 b1 = *(const float4*)(bp + k0 + 4);
        float4 b2 = *(const float4*)(bp + k0 + 8);
        float4 b3 = *(const float4*)(bp + k0 + 12);
        *(short8*)&Ab[row][kk]     = pack8(a0, a1);
        *(short8*)&Ab[row][kk + 8] = pack8(a2, a3);
        *(short8*)&Bb[row][kk]     = pack8(b0, b1);
        *(short8*)&Bb[row][kk + 8] = pack8(b2, b3);
        __syncthreads();
#pragma unroll
        for (int kt = 0; kt < 2; ++kt) {
            int k8 = kt * 32 + (lane >> 4) * 8;
            short8 fa0 = *(const short8*)&Ab[wm * 32 + (lane & 15)][k8];
            short8 fa1 = *(const short8*)&Ab[wm * 32 + 16 + (lane & 15)][k8];
            short8 fb0 = *(const short8*)&Bb[wn * 32 + (lane & 15)][k8];
            short8 fb1 = *(const short8*)&Bb[wn * 32 + 16 + (lane & 15)][k8];
            acc[0][0] = __builtin_amdgcn_mfma_f32_16x16x32_bf16(fa0, fb0, acc[0][0], 0, 0, 0);
            acc[0][1] = __builtin_amdgcn_mfma_f32_16x16x32_bf16(fa0, fb1, acc[0][1], 0, 0, 0);
            acc[1][0] = __builtin_amdgcn_mfma_f32_16x16x32_bf16(fa1, fb0, acc[1][0], 0, 0, 0);
            acc[1][1] = __builtin_amdgcn_mfma_f32_16x16x32_bf16(fa1, fb1, acc[1][1], 0, 0, 0);
        }
        __syncthreads();
    }

#pragma unroll
    for (int i = 0; i < 2; ++i)
#pragma unroll
        for (int j = 0; j < 2; ++j)
#pragma unroll
            for (int r = 0; r < 4; ++r) {
                int lrow = wm * 32 + i * 16 + (lane >> 4) * 4 + r;
                int gcol = tn + wn * 32 + j * 16 + (lane & 15);
                xW[(size_t)(tm + lrow) * GG + gcol] =
                    acc[i][j][r] + bih[gcol] + bhh[gcol];
            }
}

// ---------------- generic bf16 MFMA NT GEMM (f32 A/B) ----------------------
__global__ __launch_bounds__(256) void gemm_bf16_nt(
        const float* __restrict__ A, const float* __restrict__ Bm,
        float* __restrict__ C, int K, int lda, int ldb, int ldc,
        long sA, long sB, long sC, int Nlim,
        const float* __restrict__ bias1,
        const int* __restrict__ firstpos, const float* __restrict__ emb_mask,
        int fscol) {
    int bz = blockIdx.z;
    A += (size_t)bz * sA; Bm += (size_t)bz * sB; C += (size_t)bz * sC;
    int tm = blockIdx.y * 64, tn = blockIdx.x * 64;
    __shared__ short Ab[64][72];
    __shared__ short Bb[64][72];
    __shared__ float sfs[64];
    int tid = threadIdx.x, lane = tid & 63, wid = tid >> 6;
    int wm = wid & 1, wn = wid >> 1;

    if (fscol >= 0 && tid < 64) sfs[tid] = A[(size_t)(tm + tid) * lda + fscol];

    f32x4 zero = {0.f, 0.f, 0.f, 0.f};
    f32x4 acc[2][2] = {{zero, zero}, {zero, zero}};

    int row = tid >> 2, kk = (tid & 3) * 16;
    int brow = tn + row; if (brow >= Nlim) brow = Nlim - 1;
    const float* ap = &A[(size_t)(tm + row) * lda + kk];
    const float* bp = &Bm[(size_t)brow * ldb + kk];

    for (int k0 = 0; k0 < K; k0 += 64) {
        float4 a0 = *(const float4*)(ap + k0);
        float4 a1 = *(const float4*)(ap + k0 + 4);
        float4 a2 = *(const float4*)(ap + k0 + 8);
        float4 a3 = *(const float4*)(ap + k0 + 12);
        float4 b0 = *(const float4*)(bp + k0);
        float4 b1 = *(const float4*)(bp + k0 + 4);
        float4 b2 = *(const float4*)(bp + k0 + 8);
        float4 b3 = *(const float4*)(bp + k0 + 12);
        *(short8*)&Ab[row][kk]     = pack8(a0, a1);
        *(short8*)&Ab[row][kk + 8] = pack8(a2, a3);
        *(short8*)&Bb[row][kk]     = pack8(b0, b1);
        *(short8*)&Bb[row][kk + 8] = pack8(b2, b3);
        __syncthreads();
#pragma unroll
        for (int kt = 0; kt < 2; ++kt) {
            int k8 = kt * 32 + (lane >> 4) * 8;
            short8 fa0 = *(const short8*)&Ab[wm * 32 + (lane & 15)][k8];
            short8 fa1 = *(const short8*)&Ab[wm * 32 + 16 + (lane & 15)][k8];
            short8 fb0 = *(const short8*)&Bb[wn * 32 + (lane & 15)][k8];
            short8 fb1 = *(const short8*)&Bb[wn * 32 + 16 + (lane & 15)][k8];
            acc[0][0] = __builtin_amdgcn_mfma_f32_16x16x32_bf16(fa0, fb0, acc[0][0], 0, 0, 0);
            acc[0][1] = __builtin_amdgcn_mfma_f32_16x16x32_bf16(fa0, fb1, acc[0][1], 0, 0, 0);
            acc[1][0] = __builtin_amdgcn_mfma_f32_16x16x32_bf16(fa1, fb0, acc[1][0], 0, 0, 0);
            acc[1][1] = __builtin_amdgcn_mfma_f32_16x16x32_bf16(fa1, fb1, acc[1][1], 0, 0, 0);
        }
        __syncthreads();
    }

#pragma unroll
    for (int i = 0; i < 2; ++i) {
#pragma unroll
        for (int j = 0; j < 2; ++j) {
#pragma unroll
            for (int r = 0; r < 4; ++r) {
                int lrow = wm * 32 + i * 16 + (lane >> 4) * 4 + r;
                int gcol = tn + wn * 32 + j * 16 + (lane & 15);
                if (gcol < Nlim) {
                    float v = acc[i][j][r];
                    if (bias1) v += bias1[gcol];
                    if (firstpos) {
                        int grow = tm + lrow;
                        if (firstpos[(size_t)bz * NN_ + gcol] < grow) v += sfs[lrow];
                        v -= (1.0f - emb_mask[(size_t)bz * NN_ + gcol]) * 1e20f;
                    }
                    C[(size_t)(tm + lrow) * ldc + gcol] = v;
                }
            }
        }
    }
}

// ---------------- dec = hs16(bf16) @ Wdt^T + bdt ---------------------------
__global__ __launch_bounds__(256) void gemm_dec(
        const unsigned int* __restrict__ hs16, const float* __restrict__ Wdt,
        float* __restrict__ dec, const float* __restrict__ bdt) {
    int tm = blockIdx.y * 64, tn = blockIdx.x * 64;
    __shared__ short Ab[64][72];
    __shared__ short Bb[64][72];
    int tid = threadIdx.x, lane = tid & 63, wid = tid >> 6;
    int wm = wid & 1, wn = wid >> 1;
    f32x4 zero = {0.f, 0.f, 0.f, 0.f};
    f32x4 acc[2][2] = {{zero, zero}, {zero, zero}};
    int row = tid >> 2, kk = (tid & 3) * 16;
    const short* ap16 = (const short*)hs16 + (size_t)(tm + row) * DD + kk;
    const float* bp = Wdt + (size_t)(tn + row) * DD + kk;

    for (int k0 = 0; k0 < DD; k0 += 64) {
        *(short8*)&Ab[row][kk]     = *(const short8*)(ap16 + k0);
        *(short8*)&Ab[row][kk + 8] = *(const short8*)(ap16 + k0 + 8);
        float4 b0 = *(const float4*)(bp + k0);
        float4 b1 = *(const float4*)(bp + k0 + 4);
        float4 b2 = *(const float4*)(bp + k0 + 8);
        float4 b3 = *(const float4*)(bp + k0 + 12);
        *(short8*)&Bb[row][kk]     = pack8(b0, b1);
        *(short8*)&Bb[row][kk + 8] = pack8(b2, b3);
        __syncthreads();
#pragma unroll
        for (int kt = 0; kt < 2; ++kt) {
            int k8 = kt * 32 + (lane >> 4) * 8;
            short8 fa0 = *(const short8*)&Ab[wm * 32 + (lane & 15)][k8];
            short8 fa1 = *(const short8*)&Ab[wm * 32 + 16 + (lane & 15)][k8];
            short8 fb0 = *(const short8*)&Bb[wn * 32 + (lane & 15)][k8];
            short8 fb1 = *(const short8*)&Bb[wn * 32 + 16 + (lane & 15)][k8];
            acc[0][0] = __builtin_amdgcn_mfma_f32_16x16x32_bf16(fa0, fb0, acc[0][0], 0, 0, 0);
            acc[0][1] = __builtin_amdgcn_mfma_f32_16x16x32_bf16(fa0, fb1, acc[0][1], 0, 0, 0);
            acc[1][0] = __builtin_amdgcn_mfma_f32_16x16x32_bf16(fa1, fb0, acc[1][0], 0, 0, 0);
            acc[1][1] = __builtin_amdgcn_mfma_f32_16x16x32_bf16(fa1, fb1, acc[1][1], 0, 0, 0);
        }
        __syncthreads();
    }

#pragma unroll
    for (int i = 0; i < 2; ++i)
#pragma unroll
        for (int j = 0; j < 2; ++j)
#pragma unroll
            for (int r = 0; r < 4; ++r) {
                int lrow = wm * 32 + i * 16 + (lane >> 4) * 4 + r;
                int gcol = tn + wn * 32 + j * 16 + (lane & 15);
                dec[(size_t)(tm + lrow) * DD + gcol] = acc[i][j][r] + bdt[gcol];
            }
}

// ---------------- feat = [hs16 | attn] @ Wf^T + bf (fused cat) -------------
__global__ __launch_bounds__(256) void gemm_feat(
        const unsigned int* __restrict__ hs16, const float* __restrict__ attn,
        const float* __restrict__ Wf, const float* __restrict__ bf,
        float* __restrict__ feat) {
    int tm = blockIdx.y * 64, tn = blockIdx.x * 64;
    __shared__ short Ab[64][72];
    __shared__ short Bb[64][72];
    int tid = threadIdx.x, lane = tid & 63, wid = tid >> 6;
    int wm = wid & 1, wn = wid >> 1;
    f32x4 zero = {0.f, 0.f, 0.f, 0.f};
    f32x4 acc[2][2] = {{zero, zero}, {zero, zero}};
    int row = tid >> 2, kk = (tid & 3) * 16;
    int brow = tn + row; if (brow > 256) brow = 256;
    const short* a16 = (const short*)hs16 + (size_t)(tm + row) * DD + kk;
    const float* af  = attn + (size_t)(tm + row) * DD + kk;
    const float* bp  = Wf + (size_t)brow * (2 * DD) + kk;

    for (int k0 = 0; k0 < 2 * DD; k0 += 64) {
        if (k0 < DD) {
            *(short8*)&Ab[row][kk]     = *(const short8*)(a16 + k0);
            *(short8*)&Ab[row][kk + 8] = *(const short8*)(a16 + k0 + 8);
        } else {
            float4 a0 = *(const float4*)(af + k0 - DD);
            float4 a1 = *(const float4*)(af + k0 - DD + 4);
            float4 a2 = *(const float4*)(af + k0 - DD + 8);
            float4 a3 = *(const float4*)(af + k0 - DD + 12);
            *(short8*)&Ab[row][kk]     = pack8(a0, a1);
            *(short8*)&Ab[row][kk + 8] = pack8(a2, a3);
        }
        float4 b0 = *(const float4*)(bp + k0);
        float4 b1 = *(const float4*)(bp + k0 + 4);
        float4 b2 = *(const float4*)(bp + k0 + 8);
        float4 b3 = *(const float4*)(bp + k0 + 12);
        *(short8*)&Bb[row][kk]     = pack8(b0, b1);
        *(short8*)&Bb[row][kk + 8] = pack8(b2, b3);
        __syncthreads();
#pragma unroll
        for (int kt = 0; kt < 2; ++kt) {
            int k8 = kt * 32 + (lane >> 4) * 8;
            short8 fa0 = *(const short8*)&Ab[wm * 32 + (lane & 15)][k8];
            short8 fa1 = *(const short8*)&Ab[wm * 32 + 16 + (lane & 15)][k8];
            short8 fb0 = *(const short8*)&Bb[wn * 32 + (lane & 15)][k8];
            short8 fb1 = *(const short8*)&Bb[wn * 32 + 16 + (lane & 15)][k8];
            acc[0][0] = __builtin_amdgcn_mfma_f32_16x16x32_bf16(fa0, fb0, acc[0][0], 0, 0, 0);
            acc[0][1] = __builtin_amdgcn_mfma_f32_16x16x32_bf16(fa0, fb1, acc[0][1], 0, 0, 0);
            acc[1][0] = __builtin_amdgcn_mfma_f32_16x16x32_bf16(fa1, fb0, acc[1][0], 0, 0, 0);
            acc[1][1] = __builtin_amdgcn_mfma_f32_16x16x32_bf16(fa1, fb1, acc[1][1], 0, 0, 0);
        }
        __syncthreads();
    }

#pragma unroll
    for (int i = 0; i < 2; ++i)
#pragma unroll
        for (int j = 0; j < 2; ++j)
#pragma unroll
            for (int r = 0; r < 4; ++r) {
                int lrow = wm * 32 + i * 16 + (lane >> 4) * 4 + r;
                int gcol = tn + wn * 32 + j * 16 + (lane & 15);
                if (gcol < DD + 1)
                    feat[(size_t)(tm + lrow) * FLD + gcol] = acc[i][j][r] + bf[gcol];
            }
}

// ---------------- flash attention: raw+softmax+attn fused ------------------
// Block (c, b): s-chunk c (256 s-positions) of batch b. No max-subtraction
// (softmax is shift-invariant; |raw| <= ~30 so exp stays in f32 range; bf16
// has scale-free relative precision). Per 64-s tile: stage enc tile bf16 in
// LDS (used as K via vector reads AND as V via transposed scalar reads),
// S = Q@K^T (MFMA), P = exp(S - mask*1e20), l += rowsum(P), acc += P@V.
// Partials (acc, l) merged by k_amerge: attn = sum_c acc_c / sum_c l_c.
__global__ __launch_bounds__(256) void k_flash(const float* __restrict__ dec,
                                               const float* __restrict__ enc,
                                               const float* __restrict__ enc_mask,
                                               float* __restrict__ part,
                                               float* __restrict__ lsum) {
    int c = blockIdx.x;            // s-chunk 0..7
    int b = blockIdx.z;
    const float* Qf = dec + (size_t)b * TT * DD;
    const float* Eb = enc + (size_t)b * SS * DD;

    __shared__ short Vt[64][264];  // enc tile bf16 [s][d]
    __shared__ short Pt[64][72];   // P bf16 [t][s]
    __shared__ float l_run[64][2];
    __shared__ float smsk[64];

    int tid = threadIdx.x, lane = tid & 63, wid = tid >> 6;
    int wm = wid & 1, wn = wid >> 1;
    int row = tid >> 2, kk = (tid & 3) * 16;

    // Q as persistent A-frags (rows wm*32+(lane&15) and +16, k = kt*32+(lane>>4)*8)
    short8 qf[8][2];
#pragma unroll
    for (int kt = 0; kt < 8; ++kt) {
        int kb = kt * 32 + (lane >> 4) * 8;
        const float* q0 = Qf + (size_t)(wm * 32 + (lane & 15)) * DD + kb;
        const float* q1 = Qf + (size_t)(wm * 32 + 16 + (lane & 15)) * DD + kb;
        qf[kt][0] = pack8(*(const float4*)q0, *(const float4*)(q0 + 4));
        qf[kt][1] = pack8(*(const float4*)q1, *(const float4*)(q1 + 4));
    }

    if (tid < 128) ((float*)l_run)[tid] = 0.0f;

    f32x4 zero = {0.f, 0.f, 0.f, 0.f};
    f32x4 aO[4][2][2];
#pragma unroll
    for (int dp = 0; dp < 4; ++dp)
#pragma unroll
        for (int i = 0; i < 2; ++i)
#pragma unroll
            for (int j = 0; j < 2; ++j) aO[dp][i][j] = zero;

    for (int kt64 = 0; kt64 < 4; ++kt64) {
        int s0 = c * 256 + kt64 * 64;
        __syncthreads();   // prior tile's reads done
        // stage enc tile -> bf16 Vt, and mask slice
#pragma unroll
        for (int kq = 0; kq < 4; ++kq) {
            const float* e = Eb + (size_t)(s0 + row) * DD + kq * 64 + kk;
            float4 e0 = *(const float4*)e;
            float4 e1 = *(const float4*)(e + 4);
            float4 e2 = *(const float4*)(e + 8);
            float4 e3 = *(const float4*)(e + 12);
            *(short8*)&Vt[row][kq * 64 + kk]     = pack8(e0, e1);
            *(short8*)&Vt[row][kq * 64 + kk + 8] = pack8(e2, e3);
        }
        if (tid < 64) smsk[tid] = enc_mask[(size_t)b * SS + s0 + tid];
        __syncthreads();

        // S = Q @ K^T  (64t x 64s)
        f32x4 aS[2][2] = {{zero, zero}, {zero, zero}};
#pragma unroll
        for (int kt = 0; kt < 8; ++kt) {
            int k8 = kt * 32 + (lane >> 4) * 8;
            short8 fb0 = *(const short8*)&Vt[wn * 32 + (lane & 15)][k8];
            short8 fb1 = *(const short8*)&Vt[wn * 32 + 16 + (lane & 15)][k8];
            aS[0][0] = __builtin_amdgcn_mfma_f32_16x16x32_bf16(qf[kt][0], fb0, aS[0][0], 0, 0, 0);
            aS[0][1] = __builtin_amdgcn_mfma_f32_16x16x32_bf16(qf[kt][0], fb1, aS[0][1], 0, 0, 0);
            aS[1][0] = __builtin_amdgcn_mfma_f32_16x16x32_bf16(qf[kt][1], fb0, aS[1][0], 0, 0, 0);
            aS[1][1] = __builtin_amdgcn_mfma_f32_16x16x32_bf16(qf[kt][1], fb1, aS[1][1], 0, 0, 0);
        }

        // P = exp(S - maskpen); row-sums into l_run; P -> Pt (bf16)
        int scol0 = wn * 32 + (lane & 15);
        float pen0 = (1.0f - smsk[scol0]) * 1e20f;
        float pen1 = (1.0f - smsk[scol0 + 16]) * 1e20f;
#pragma unroll
        for (int i = 0; i < 2; ++i)
#pragma unroll
            for (int r = 0; r < 4; ++r) {
                float p0 = __expf(aS[i][0][r] - pen0);
                float p1 = __expf(aS[i][1][r] - pen1);
                int trow = wm * 32 + i * 16 + (lane >> 4) * 4 + r;
                Pt[trow][scol0] = (short)f2bf(p0);
                Pt[trow][scol0 + 16] = (short)f2bf(p1);
                float rs = p0 + p1;
                rs += __shfl_xor(rs, 1);
                rs += __shfl_xor(rs, 2);
                rs += __shfl_xor(rs, 4);
                rs += __shfl_xor(rs, 8);
                if ((lane & 15) == 0) l_run[trow][wn] += rs;
            }
        __syncthreads();

        // acc += P @ V  (64t x 256d, k = 64s)
#pragma unroll
        for (int kt = 0; kt < 2; ++kt) {
            int k8 = kt * 32 + (lane >> 4) * 8;
            short8 fa0 = *(const short8*)&Pt[wm * 32 + (lane & 15)][k8];
            short8 fa1 = *(const short8*)&Pt[wm * 32 + 16 + (lane & 15)][k8];
#pragma unroll
            for (int dp = 0; dp < 4; ++dp) {
                int dc = dp * 64 + wn * 32 + (lane & 15);
                short8 fb0, fb1;
#pragma unroll
                for (int e = 0; e < 8; ++e) {
                    fb0[e] = Vt[k8 + e][dc];
                    fb1[e] = Vt[k8 + e][dc + 16];
                }
                aO[dp][0][0] = __builtin_amdgcn_mfma_f32_16x16x32_bf16(fa0, fb0, aO[dp][0][0], 0, 0, 0);
                aO[dp][0][1] = __builtin_amdgcn_mfma_f32_16x16x32_bf16(fa0, fb1, aO[dp][0][1], 0, 0, 0);
                aO[dp][1][0] = __builtin_amdgcn_mfma_f32_16x16x32_bf16(fa1, fb0, aO[dp][1][0], 0, 0, 0);
                aO[dp][1][1] = __builtin_amdgcn_mfma_f32_16x16x32_bf16(fa1, fb1, aO[dp][1][1], 0, 0, 0);
            }
        }
    }
    __syncthreads();

    // write partials
    float* pp = part + ((size_t)(b * 8 + c) * 64) * 256;
#pragma unroll
    for (int dp = 0; dp < 4; ++dp)
#pragma unroll
        for (int i = 0; i < 2; ++i)
#pragma unroll
            for (int j = 0; j < 2; ++j)
#pragma unroll
                for (int r = 0; r < 4; ++r) {
                    int trow = wm * 32 + i * 16 + (lane >> 4) * 4 + r;
                    int dcol = dp * 64 + wn * 32 + j * 16 + (lane & 15);
                    pp[(size_t)trow * 256 + dcol] = aO[dp][i][j][r];
                }
    if (tid < 64)
        lsum[(size_t)(b * 8 + c) * 64 + tid] = l_run[tid][0] + l_run[tid][1];
}

// ---------------- merge flash partials: attn = sum acc_c / sum l_c ---------
__global__ __launch_bounds__(256) void k_amerge(const float* __restrict__ part,
                                                const float* __restrict__ lsum,
                                                float* __restrict__ attn) {
    int bt = blockIdx.x;           // 0..2047
    int b = bt >> 6, t = bt & 63, d = threadIdx.x;
    float a = 0.0f, L = 0.0f;
#pragma unroll
    for (int c = 0; c < 8; ++c) {
        a += part[((size_t)(b * 8 + c) * 64 + t) * 256 + d];
        L += lsum[(size_t)(b * 8 + c) * 64 + t];
    }
    attn[(size_t)bt * 256 + d] = a / L;
}

// ---------------- LSTM (proven round-6): transposed MFMA, in-lane act ------
__global__ __launch_bounds__(256) void k_lstm_mfma(const float* __restrict__ xW,
                                                   const float* __restrict__ Whh,
                                                   unsigned int* __restrict__ hbuf32,
                                                   unsigned int* __restrict__ hs16) {
    int p = blockIdx.x;            // 0..31 col-slice
    int tid = threadIdx.x;
    int lane = tid & 63;
    int wid = tid >> 6;            // 4 waves
    int mi = wid & 1;              // unit-halves (4 units each)
    int ni = wid >> 1;             // batch-halves (16 batches each)
    int jj = lane >> 4;            // 0..3 unit within mi-group
    int bl = lane & 15;            // batch within ni-group
    int j = p * 8 + mi * 4 + jj;   // hidden unit this lane activates
    int b = ni * 16 + bl;          // batch this lane activates

    short8 afrag[8];
    {
        int rr = lane & 15;
        const float* wrow = Whh + (size_t)((rr & 3) * 256 + p * 8 + mi * 4 + (rr >> 2)) * DD;
#pragma unroll
        for (int kt = 0; kt < 8; ++kt) {
            short8 f;
#pragma unroll
            for (int e = 0; e < 8; ++e)
                f[e] = (short)f2bf(wrow[kt * 32 + (lane >> 4) * 8 + e]);
            afrag[kt] = f;
        }
    }

    float cstate = 0.0f;
    const int wb = jj * 128 + b;   // word base: (jj*4 + w4)*32 + b

    for (int t = 0; t < TT; ++t) {
        const float* g0 = xW + ((size_t)b * TT + t) * GG + j;
        float xb0 = g0[0], xb1 = g0[256], xb2 = g0[512], xb3 = g0[768];

        f32x4 acc = {0.f, 0.f, 0.f, 0.f};
        if (t > 0) {
            const unsigned int* hb = hbuf32 + (size_t)(t - 1) * 4096;
            unsigned int q[32];
            bool ready = false;
            while (!ready) {
                ready = true;
#pragma unroll
                for (int kt = 0; kt < 8; ++kt)
#pragma unroll
                    for (int w4 = 0; w4 < 4; ++w4)
                        q[kt * 4 + w4] = __hip_atomic_load(&hb[kt * 512 + wb + w4 * 32],
                            __ATOMIC_RELAXED, __HIP_MEMORY_SCOPE_AGENT);
#pragma unroll
                for (int i = 0; i < 32; ++i) ready = ready && ok32(q[i]);
            }
#pragma unroll
            for (int kt = 0; kt < 8; ++kt) {
                union { unsigned int w[4]; short8 s; } u;
                u.w[0] = q[kt * 4 + 0]; u.w[1] = q[kt * 4 + 1];
                u.w[2] = q[kt * 4 + 2]; u.w[3] = q[kt * 4 + 3];
                acc = __builtin_amdgcn_mfma_f32_16x16x32_bf16(afrag[kt], u.s, acc, 0, 0, 0);
            }
        }

        float pi = xb0 + acc[0];
        float pf = xb1 + acc[1];
        float pg = xb2 + acc[2];
        float po = xb3 + acc[3];
        float ig = 1.0f / (1.0f + __expf(-pi));
        float fg = 1.0f / (1.0f + __expf(-pf));
        float gg = tanhf(pg);
        float og = 1.0f / (1.0f + __expf(-po));
        cstate = fg * cstate + ig * gg;
        float hn = og * tanhf(cstate);

        float hnb = __shfl_down(hn, 16);
        if ((jj & 1) == 0) {
            unsigned int wv = (unsigned int)f2bf(hn) |
                              ((unsigned int)f2bf(hnb) << 16);
            int jp = p * 4 + mi * 2 + (jj >> 1);
            __hip_atomic_store(&hbuf32[(size_t)t * 4096 + jp * 32 + b],
                               wv, __ATOMIC_RELAXED, __HIP_MEMORY_SCOPE_AGENT);
            hs16[((size_t)b * TT + t) * 128 + jp] = wv;   // row-major bf16 hs
        }
        asm volatile("s_waitcnt vmcnt(0)" ::: "memory");
    }
}

// ---------------- launch ----------------
extern "C" void kernel_launch(void* const* d_in, const int* in_sizes, int n_in,
                              void* d_out, int out_size, void* d_ws, size_t ws_size,
                              hipStream_t stream) {
    const float* emb      = (const float*)d_in[0];
    const float* emb_mask = (const float*)d_in[1];
    const float* enc      = (const float*)d_in[2];
    const float* enc_mask = (const float*)d_in[3];
    const int*   gt       = (const int*)d_in[4];
    const float* go       = (const float*)d_in[5];
    const float* Wih      = (const float*)d_in[6];
    const float* Whh      = (const float*)d_in[7];
    const float* bih      = (const float*)d_in[8];
    const float* bhh      = (const float*)d_in[9];
    const float* Wdt      = (const float*)d_in[10];
    const float* bdt      = (const float*)d_in[11];
    const float* Wf       = (const float*)d_in[12];
    const float* bf       = (const float*)d_in[13];
    float* out = (float*)d_out;

    float* ws    = (float*)d_ws;
    float* xW    = ws;                                   // [B*T*G]     2.10M
    float* dec   = xW   + (size_t)BB * TT * GG;          // [B*T*D]     0.52M
    float* attn  = dec  + (size_t)BB * TT * DD;          // [B*T*D]     0.52M
    float* feat  = attn + (size_t)BB * TT * DD;          // [B*T*FLD]   0.54M
    float* part  = feat + (size_t)BB * TT * FLD;         // [B*8*T*D]   4.19M
    float* lsum  = part + (size_t)BB * 8 * TT * DD;      // [B*8*T]     16K
    int* firstpos = (int*)(lsum + (size_t)BB * 8 * TT);  // [B*N]
    unsigned int* hbuf32 = (unsigned int*)(firstpos + (size_t)BB * NN_); // [T*4096]
    unsigned int* hs16   = hbuf32 + (size_t)TT * 4096;   // [B*T*128]

    // prep: firstpos scan + hbuf poison
    k_prep<<<256, 256, 0, stream>>>(gt, firstpos, hbuf32);

    // xW = x @ Wih^T + bih + bhh (gather fused) : [2048,1024]
    gemm_xw<<<dim3(GG / 64, BB * TT / 64, 1), 256, 0, stream>>>(
        emb, gt, go, Wih, xW, bih, bhh);

    k_lstm_mfma<<<LP, 256, 0, stream>>>(xW, Whh, hbuf32, hs16);

    // dec = hs16 @ Wdt^T + bdt : [2048,256]
    gemm_dec<<<dim3(DD / 64, BB * TT / 64, 1), 256, 0, stream>>>(
        hs16, Wdt, dec, bdt);

    // fused attention: partials over 8 s-chunks per batch, then merge
    k_flash<<<dim3(8, 1, BB), 256, 0, stream>>>(dec, enc, enc_mask, part, lsum);
    k_amerge<<<BB * TT, 256, 0, stream>>>(part, lsum, attn);

    // feat = [hs16|attn] @ Wf^T + bf : [2048, 257] (cat fused, ld FLD)
    gemm_feat<<<dim3(5, BB * TT / 64, 1), 256, 0, stream>>>(
        hs16, attn, Wf, bf, feat);

    // score[b] = feat[b,:, :256] @ emb[b]^T (+ picked, mask)
    gemm_bf16_nt<<<dim3(NN_ / 64, 1, BB), 256, 0, stream>>>(
        feat, emb, out, DD, FLD, DD, NN_,
        (long)TT * FLD, (long)NN_ * DD, (long)TT * NN_, NN_,
        nullptr, firstpos, emb_mask, 256);
}